// Round 4
// baseline (355.764 us; speedup 1.0000x reference)
//
#include <hip/hip_runtime.h>
#include <math.h>

#define D_MODEL 1024
#define HEADS   16
#define HDIM    64
#define CHUNK   128
#define B_SZ    4
#define L_SEQ   2048
#define NCHUNK  16
#define NTOK    8192
#define EPS_DEN 1e-3f

typedef _Float16 half8 __attribute__((ext_vector_type(8)));
typedef _Float16 half4 __attribute__((ext_vector_type(4)));
typedef float    f32x4 __attribute__((ext_vector_type(4)));

__device__ __forceinline__ void gld_lds16(const void* g, void* l) {
    __builtin_amdgcn_global_load_lds(
        (const __attribute__((address_space(1))) void*)g,
        (__attribute__((address_space(3))) void*)l, 16, 0, 0);
}

// ---------------------------------------------------------------------------
// Fused preprocessing: x->hi|lo, Wq->hi|lo, Wk->hi|lo, Wv->f16, Wo->f16,
// bias concat [bq|bk].
// ---------------------------------------------------------------------------
__global__ __launch_bounds__(256) void prep(
    const float* __restrict__ x,  const float* __restrict__ Wq,
    const float* __restrict__ Wk, const float* __restrict__ Wv,
    const float* __restrict__ Wo, const float* __restrict__ bq,
    const float* __restrict__ bk,
    _Float16* __restrict__ x2,  _Float16* __restrict__ w2q,
    _Float16* __restrict__ w2k, _Float16* __restrict__ wv16,
    _Float16* __restrict__ wo16, float* __restrict__ bqk) {
    const int bid = blockIdx.x;
    if (bid < 5120) {           // split jobs: x / Wq / Wk
        const float* src; _Float16* dst; int t;
        if (bid < 4096)      { src = x;  dst = x2;  t = bid * 256 + threadIdx.x; }
        else if (bid < 4608) { src = Wq; dst = w2q; t = (bid - 4096) * 256 + threadIdx.x; }
        else                 { src = Wk; dst = w2k; t = (bid - 4608) * 256 + threadIdx.x; }
        int m = t >> 7, kc = (t & 127) << 3;
        const float* s = src + (size_t)m * 1024 + kc;
        f32x4 a = *(const f32x4*)s;
        f32x4 b = *(const f32x4*)(s + 4);
        float xs[8] = {a.x, a.y, a.z, a.w, b.x, b.y, b.z, b.w};
        half8 hi, lo;
        #pragma unroll
        for (int u = 0; u < 8; ++u) {
            _Float16 h = (_Float16)xs[u];
            hi[u] = h;
            lo[u] = (_Float16)(xs[u] - (float)h);
        }
        *(half8*)(dst + (size_t)m * 2048 + kc)        = hi;
        *(half8*)(dst + (size_t)m * 2048 + 1024 + kc) = lo;
    } else if (bid < 6144) {    // conv jobs: Wv / Wo
        const float* src; _Float16* dst; int t;
        if (bid < 5632) { src = Wv; dst = wv16; t = (bid - 5120) * 256 + threadIdx.x; }
        else            { src = Wo; dst = wo16; t = (bid - 5632) * 256 + threadIdx.x; }
        int m = t >> 7, kc = (t & 127) << 3;
        const float* s = src + (size_t)m * 1024 + kc;
        f32x4 a = *(const f32x4*)s;
        f32x4 b = *(const f32x4*)(s + 4);
        float xs[8] = {a.x, a.y, a.z, a.w, b.x, b.y, b.z, b.w};
        half8 hv;
        #pragma unroll
        for (int u = 0; u < 8; ++u) hv[u] = (_Float16)xs[u];
        *(half8*)(dst + (size_t)m * 1024 + kc) = hv;
    } else {
        int i = (bid - 6144) * 256 + threadIdx.x;
        bqk[i] = (i < 1024) ? bq[i] : bk[i - 1024];
    }
}

// ---------------------------------------------------------------------------
// Fused q/k/v projection GEMM — faithful 8-phase port (T2+T3+T4+T5).
// Tile 256x256 (qk, K=3072 logical) + fused 256x128 v tail (K=1024),
// 8 waves (2M x 4N), BK=32, grid exactly 32x8 = 256 blocks = 1 per CU.
//
// Per K-step t (2 phases; bf held across phases):
//   [gate, once per step, single asm] s_waitcnt vmcnt(4); s_barrier
//     -- step t's 4 staging loads (issued at t-2) complete in EVERY wave;
//        step t+1's 4 loads stay in flight. vmcnt is per-wave, and every
//        wave issues every staging load, so vmcnt+barrier = collective gate.
//   phase0: ds_read af[0..3],bf[0..3] from slot(t%3); stage A-halves(t+2)
//           into slot((t+2)%3); s_barrier; setprio(1); 16 MFMA; setprio(0);
//           s_barrier
//   phase1: ds_read af[4..7]; stage B-halves(t+2); s_barrier; setprio(1);
//           16 MFMA; setprio(0)   [next step's gate closes the phase]
// Slot safety: slot((t+2)%3) == slot(t-1); all waves' reads of step t-1 are
// complete before they pass step t's gate barrier (MFMA data-dependence),
// and the stage is issued after it -> write lands strictly later.
// NO other VMEM op exists inside the loops (gate-count integrity).
// ---------------------------------------------------------------------------
__global__ __launch_bounds__(512, 2) void gemm_qkv(
    const _Float16* __restrict__ A,    // x2, lda 2048
    const _Float16* __restrict__ Bqk,  // [w2q;w2k], ldb 2048
    const _Float16* __restrict__ Bv,   // wv16, ldb 1024
    const float* __restrict__ bqk, const float* __restrict__ bv,
    _Float16* __restrict__ Qlo, _Float16* __restrict__ Klo,
    _Float16* __restrict__ Q16, _Float16* __restrict__ K16,
    _Float16* __restrict__ V16, float* __restrict__ ksum) {
    // 3 K-step buffers of [A 256x32 | B 256x32] = 32KB each; 96KB total.
    __shared__ __align__(16) _Float16 sbuf[3 * 16384];

    const int tid  = threadIdx.x;
    const int lane = tid & 63;
    const int w    = tid >> 6;          // 0..7
    const int bx   = blockIdx.x;        // 0..31 row-block (fastest)
    const int cb   = blockIdx.y;        // 0..7 col-block
    const int row0 = bx * 256;
    const int col0 = cb * 256;          // qk col space 0..2047
    const int isk  = (cb >= 4);
    const int wm   = (w & 1) * 128;     // wave M-half
    const int wn   = (w >> 1) * 64;     // wave N-quarter (qk)
    const int wnv  = (w >> 1) * 32;     // wave N-quarter (v)
    const int ml   = lane & 15;
    const int kg   = lane >> 4;

    // staging source (per-thread): row rS 0..127, 16B chunk cS (XOR swizzle)
    const int rS = tid >> 2;
    const int cS = (tid & 3) ^ ((rS >> 1) & 3);
    const _Float16* gA0 = A   + (size_t)(row0 + rS) * 2048 + cS * 8;
    const _Float16* gA1 = gA0 + (size_t)128 * 2048;
    const _Float16* gB0 = Bqk + (size_t)(col0 + rS) * 2048 + cS * 8;
    const _Float16* gB1 = gB0 + (size_t)128 * 2048;
    const _Float16* gBv = Bv  + (size_t)(cb * 128 + rS) * 1024 + cS * 8;

    // ds_read offsets (halves). A region: rows 0..255 at 0; B region at 8192.
    int offA[8], offB[4], offBv[2];
    #pragma unroll
    for (int i = 0; i < 8; ++i) {
        int r = wm + i * 16 + ml;
        offA[i] = r * 32 + (kg ^ ((r >> 1) & 3)) * 8;
    }
    #pragma unroll
    for (int j = 0; j < 4; ++j) {
        int rn = wn + j * 16 + ml;
        offB[j] = 8192 + rn * 32 + (kg ^ ((rn >> 1) & 3)) * 8;
    }
    #pragma unroll
    for (int j = 0; j < 2; ++j) {
        int rn = wnv + j * 16 + ml;
        offBv[j] = 8192 + rn * 32 + (kg ^ ((rn >> 1) & 3)) * 8;
    }

    // ---------------- qk main loop: 96 K-steps ----------------
    f32x4 acc[8][4];
    #pragma unroll
    for (int i = 0; i < 8; ++i)
        #pragma unroll
        for (int j = 0; j < 4; ++j) { f32x4 z = {0.f,0.f,0.f,0.f}; acc[i][j] = z; }

    auto stageQK_A = [&](int t, int slot) {
        const int k0 = t * 32;
        const int acol = (k0 < 2048) ? k0 : k0 - 2048;
        _Float16* l = sbuf + slot * 16384 + w * 512;
        gld_lds16(gA0 + acol, l);
        gld_lds16(gA1 + acol, l + 4096);
    };
    auto stageQK_B = [&](int t, int slot) {
        const int k0 = t * 32;
        const int bcol = (k0 < 1024) ? k0 : k0 - 1024;
        _Float16* l = sbuf + slot * 16384 + w * 512;
        gld_lds16(gB0 + bcol, l + 8192);
        gld_lds16(gB1 + bcol, l + 12288);
    };

    stageQK_A(0, 0); stageQK_B(0, 0);
    stageQK_A(1, 1); stageQK_B(1, 1);
    int slr = 0, sln = 2;
    for (int t = 0; t < 96; ++t) {
        if (t + 1 < 96) asm volatile("s_waitcnt vmcnt(4)\n\ts_barrier" ::: "memory");
        else            asm volatile("s_waitcnt vmcnt(0)\n\ts_barrier" ::: "memory");
        const _Float16* lb = sbuf + slr * 16384;
        // ---- phase 0
        half8 af[4], bf[4];
        #pragma unroll
        for (int i = 0; i < 4; ++i) af[i] = *(const half8*)&lb[offA[i]];
        #pragma unroll
        for (int j = 0; j < 4; ++j) bf[j] = *(const half8*)&lb[offB[j]];
        if (t + 2 < 96) stageQK_A(t + 2, sln);
        asm volatile("s_barrier" ::: "memory");
        __builtin_amdgcn_s_setprio(1);
        #pragma unroll
        for (int i = 0; i < 4; ++i)
            #pragma unroll
            for (int j = 0; j < 4; ++j)
                acc[i][j] = __builtin_amdgcn_mfma_f32_16x16x32_f16(af[i], bf[j], acc[i][j], 0, 0, 0);
        __builtin_amdgcn_s_setprio(0);
        asm volatile("s_barrier" ::: "memory");
        // ---- phase 1
        half8 ag[4];
        #pragma unroll
        for (int i = 0; i < 4; ++i) ag[i] = *(const half8*)&lb[offA[4 + i]];
        if (t + 2 < 96) stageQK_B(t + 2, sln);
        asm volatile("s_barrier" ::: "memory");
        __builtin_amdgcn_s_setprio(1);
        #pragma unroll
        for (int i = 0; i < 4; ++i)
            #pragma unroll
            for (int j = 0; j < 4; ++j)
                acc[4 + i][j] = __builtin_amdgcn_mfma_f32_16x16x32_f16(ag[i], bf[j], acc[4 + i][j], 0, 0, 0);
        __builtin_amdgcn_s_setprio(0);
        slr = (slr == 2) ? 0 : slr + 1;
        sln = (sln == 2) ? 0 : sln + 1;
    }

    // ---------------- v prologue (overlaps qk epilogue) ----------------
    auto stageV_A = [&](int t, int slot) {
        const int k0 = t * 32;
        _Float16* l = sbuf + slot * 16384 + w * 512;
        gld_lds16(gA0 + k0, l);
        gld_lds16(gA1 + k0, l + 4096);
    };
    auto stageV_B = [&](int t, int slot) {
        gld_lds16(gBv + t * 32, sbuf + slot * 16384 + 8192 + w * 512);
    };
    // slots 0,1 last read at steps 93,94; every wave passed step 95's gate
    // barrier after consuming them -> safe to overwrite now.
    stageV_A(0, 0); stageV_B(0, 0);
    stageV_A(1, 1); stageV_B(1, 1);

    // ---------------- qk epilogue ----------------
    const int colq = isk ? col0 - 1024 : col0;
    _Float16* Ylo  = isk ? Klo : Qlo;
    _Float16* Y16  = isk ? K16 : Q16;

    #pragma unroll
    for (int j = 0; j < 4; ++j) {
        const float bvb = bqk[col0 + wn + j * 16 + ml];
        const int nn = colq + wn + j * 16 + ml;
        #pragma unroll
        for (int i = 0; i < 8; ++i) {
            #pragma unroll
            for (int tt = 0; tt < 4; ++tt) {
                float vv = acc[i][j][tt] + bvb;
                vv = vv / (1.f + expf(-vv));         // silu
                int mm = row0 + wm + i * 16 + kg * 4 + tt;
                _Float16 hv = (_Float16)vv;          // hi (same cast as slab)
                Ylo[(size_t)mm * 1024 + nn] = (_Float16)(vv - (float)hv);
                acc[i][j][tt] = vv;
            }
        }
    }

    // fused ksum for k-blocks: each wave's 128 rows = exactly one chunk.
    if (isk) {
        const int bb = (row0 + wm) >> 11;
        const int nc = ((row0 + wm) >> 7) & 15;
        #pragma unroll
        for (int j = 0; j < 4; ++j) {
            float ps = 0.f;
            #pragma unroll
            for (int i = 0; i < 8; ++i)
                #pragma unroll
                for (int tt = 0; tt < 4; ++tt) ps += acc[i][j][tt];
            ps += __shfl_xor(ps, 16, 64);
            ps += __shfl_xor(ps, 32, 64);
            if (kg == 0) {
                const int cg = colq + wn + j * 16 + ml;
                const int h = cg >> 6, f = cg & 63;
                ksum[(size_t)((bb * 16 + h) * 16 + nc) * 64 + f] = ps;
            }
        }
    }

    // f16 hi via LDS slab transpose (8 slabs of 32 rows x 256 cols), slot 2.
    {
        _Float16* sl = sbuf + 32768;
        asm volatile("s_barrier" ::: "memory");   // LDS handover (reads of
        for (int s = 0; s < 8; ++s) {             // slot2 consumed pre-gate)
            if ((w & 1) == (s >> 2)) {
                const int i0 = (s & 3) * 2;
                #pragma unroll
                for (int ii = 0; ii < 2; ++ii)
                    #pragma unroll
                    for (int j = 0; j < 4; ++j)
                        #pragma unroll
                        for (int tt = 0; tt < 4; ++tt) {
                            int lr = ii * 16 + kg * 4 + tt;
                            sl[lr * 264 + wn + j * 16 + ml] = (_Float16)acc[i0 + ii][j][tt];
                        }
            }
            __syncthreads();
            {
                const int r = tid >> 4, c0 = (tid & 15) * 16;
                half8 h0 = *(const half8*)&sl[r * 264 + c0];
                half8 h1 = *(const half8*)&sl[r * 264 + c0 + 8];
                *(half8*)(Y16 + (size_t)(row0 + s * 32 + r) * 1024 + colq + c0)     = h0;
                *(half8*)(Y16 + (size_t)(row0 + s * 32 + r) * 1024 + colq + c0 + 8) = h1;
            }
            __syncthreads();
        }
    }

    // ---------------- v main loop: 32 K-steps (256x128 tile) ----------------
    f32x4 vacc[8][2];
    #pragma unroll
    for (int i = 0; i < 8; ++i)
        #pragma unroll
        for (int j = 0; j < 2; ++j) { f32x4 z = {0.f,0.f,0.f,0.f}; vacc[i][j] = z; }

    slr = 0; sln = 2;
    for (int t = 0; t < 32; ++t) {
        if (t + 1 < 32) asm volatile("s_waitcnt vmcnt(3)\n\ts_barrier" ::: "memory");
        else            asm volatile("s_waitcnt vmcnt(0)\n\ts_barrier" ::: "memory");
        const _Float16* lb = sbuf + slr * 16384;
        // ---- phase 0
        half8 af[4], bf[2];
        #pragma unroll
        for (int i = 0; i < 4; ++i) af[i] = *(const half8*)&lb[offA[i]];
        #pragma unroll
        for (int j = 0; j < 2; ++j) bf[j] = *(const half8*)&lb[offBv[j]];
        if (t + 2 < 32) stageV_A(t + 2, sln);
        asm volatile("s_barrier" ::: "memory");
        __builtin_amdgcn_s_setprio(1);
        #pragma unroll
        for (int i = 0; i < 4; ++i)
            #pragma unroll
            for (int j = 0; j < 2; ++j)
                vacc[i][j] = __builtin_amdgcn_mfma_f32_16x16x32_f16(af[i], bf[j], vacc[i][j], 0, 0, 0);
        __builtin_amdgcn_s_setprio(0);
        asm volatile("s_barrier" ::: "memory");
        // ---- phase 1
        half8 ag[4];
        #pragma unroll
        for (int i = 0; i < 4; ++i) ag[i] = *(const half8*)&lb[offA[4 + i]];
        if (t + 2 < 32) stageV_B(t + 2, sln);
        asm volatile("s_barrier" ::: "memory");
        __builtin_amdgcn_s_setprio(1);
        #pragma unroll
        for (int i = 0; i < 4; ++i)
            #pragma unroll
            for (int j = 0; j < 2; ++j)
                vacc[4 + i][j] = __builtin_amdgcn_mfma_f32_16x16x32_f16(ag[i], bf[j], vacc[4 + i][j], 0, 0, 0);
        __builtin_amdgcn_s_setprio(0);
        slr = (slr == 2) ? 0 : slr + 1;
        sln = (sln == 2) ? 0 : sln + 1;
    }

    // ---------------- v epilogue: bias + slab transpose to V16 ----------------
    #pragma unroll
    for (int j = 0; j < 2; ++j) {
        const float bvb = bv[cb * 128 + wnv + j * 16 + ml];
        #pragma unroll
        for (int i = 0; i < 8; ++i)
            #pragma unroll
            for (int tt = 0; tt < 4; ++tt) vacc[i][j][tt] += bvb;
    }
    {
        _Float16* sl = sbuf + 32768;
        asm volatile("s_barrier" ::: "memory");
        for (int s = 0; s < 8; ++s) {
            if ((w & 1) == (s >> 2)) {
                const int i0 = (s & 3) * 2;
                #pragma unroll
                for (int ii = 0; ii < 2; ++ii)
                    #pragma unroll
                    for (int j = 0; j < 2; ++j)
                        #pragma unroll
                        for (int tt = 0; tt < 4; ++tt) {
                            int lr = ii * 16 + kg * 4 + tt;
                            sl[lr * 136 + wnv + j * 16 + ml] = (_Float16)vacc[i0 + ii][j][tt];
                        }
            }
            __syncthreads();
            {
                const int r = tid >> 4, c0 = (tid & 15) * 8;
                half8 h0 = *(const half8*)&sl[r * 136 + c0];
                *(half8*)(V16 + (size_t)(row0 + s * 32 + r) * 1024 + cb * 128 + c0) = h0;
            }
            __syncthreads();
        }
    }
}

// ---------------------------------------------------------------------------
// Final output GEMM: out = attn16 * wo16^T * 64 + bo. Tile 128x128, BK=32.
// grid dim3(64, 8): x = ROW-block fastest.
// ---------------------------------------------------------------------------
__global__ __launch_bounds__(256, 4) void gemm_out(
    const _Float16* __restrict__ A,   // attn16, lda 1024
    const _Float16* __restrict__ B,   // wo16, ldb 1024
    const float* __restrict__ bias,
    float* __restrict__ Y) {
    __shared__ __align__(16) _Float16 sA[4096];   // 128 x 32
    __shared__ __align__(16) _Float16 sB[4096];   // 128 x 32

    const int tid  = threadIdx.x;
    const int lane = tid & 63;
    const int w    = tid >> 6;
    const int row0 = blockIdx.x * 128;
    const int col0 = blockIdx.y * 128;
    const int wm   = (w & 1) * 64;
    const int wn   = (w >> 1) * 64;

    const int ch0 = w * 64 + lane;
    const int rS0 = ch0 >> 2;
    const int cS0 = (ch0 & 3) ^ ((rS0 >> 1) & 3);
    const int ch1 = ch0 + 256;
    const int rS1 = ch1 >> 2;
    const int cS1 = (ch1 & 3) ^ ((rS1 >> 1) & 3);

    f32x4 acc[4][4];
    #pragma unroll
    for (int i = 0; i < 4; ++i)
        #pragma unroll
        for (int j = 0; j < 4; ++j) { f32x4 z = {0.f, 0.f, 0.f, 0.f}; acc[i][j] = z; }

    const int ml = lane & 15;
    const int kg = lane >> 4;
    int offA[4], offB[4];
    #pragma unroll
    for (int i = 0; i < 4; ++i) {
        int r  = wm + i * 16 + ml;
        offA[i] = r * 32 + (kg ^ ((r >> 1) & 3)) * 8;
        int rn = wn + i * 16 + ml;
        offB[i] = rn * 32 + (kg ^ ((rn >> 1) & 3)) * 8;
    }

    for (int kit = 0; kit < 32; ++kit) {
        const int k0 = kit * 32;
        gld_lds16(A + (size_t)(row0 + rS0) * 1024 + k0 + cS0 * 8, &sA[w * 512]);
        gld_lds16(A + (size_t)(row0 + rS1) * 1024 + k0 + cS1 * 8, &sA[2048 + w * 512]);
        gld_lds16(B + (size_t)(col0 + rS0) * 1024 + k0 + cS0 * 8, &sB[w * 512]);
        gld_lds16(B + (size_t)(col0 + rS1) * 1024 + k0 + cS1 * 8, &sB[2048 + w * 512]);
        __syncthreads();

        half8 af[4], bf[4];
        #pragma unroll
        for (int i = 0; i < 4; ++i) {
            af[i] = *(const half8*)&sA[offA[i]];
            bf[i] = *(const half8*)&sB[offB[i]];
        }
        #pragma unroll
        for (int i = 0; i < 4; ++i)
            #pragma unroll
            for (int j = 0; j < 4; ++j)
                acc[i][j] = __builtin_amdgcn_mfma_f32_16x16x32_f16(af[i], bf[j], acc[i][j], 0, 0, 0);
        __syncthreads();
    }

    const int rg = lane >> 4;
    #pragma unroll
    for (int j = 0; j < 4; ++j) {
        const int nn = col0 + wn + j * 16 + ml;
        const float bvb = bias[nn];
        #pragma unroll
        for (int i = 0; i < 4; ++i) {
            #pragma unroll
            for (int t = 0; t < 4; ++t) {
                int mm = row0 + wm + i * 16 + rg * 4 + t;
                Y[(size_t)mm * 1024 + nn] = acc[i][j][t] * 64.f + bvb;
            }
        }
    }
}

// ---------------------------------------------------------------------------
// chunk stats: kvT[blk][e][f] = sum_j v16[j][e]*k16[j][f] via MFMA.
// ---------------------------------------------------------------------------
__global__ __launch_bounds__(256) void chunk_stats(
    const _Float16* __restrict__ k16g, const _Float16* __restrict__ v16g,
    float* __restrict__ kvT) {
    const int blk = blockIdx.x;
    const int n = blk & 15, bh = blk >> 4, h = bh & 15, b = bh >> 4;
    const size_t base = ((size_t)b * L_SEQ + (size_t)n * CHUNK) * D_MODEL + (size_t)h * HDIM;

    __shared__ __align__(16) _Float16 sv[64 * 136];
    __shared__ __align__(16) _Float16 sk[64 * 136];

    const int tid = threadIdx.x;
    #pragma unroll
    for (int p = 0; p < 4; ++p) {
        int idx = p * 256 + tid;
        int j = idx >> 3, c = idx & 7;
        half8 vv = *(const half8*)(v16g + base + (size_t)j * D_MODEL + c * 8);
        half8 kk = *(const half8*)(k16g + base + (size_t)j * D_MODEL + c * 8);
        #pragma unroll
        for (int u = 0; u < 8; ++u) {
            sv[(c * 8 + u) * 136 + j] = vv[u];
            sk[(c * 8 + u) * 136 + j] = kk[u];
        }
    }
    __syncthreads();

    const int lane = tid & 63;
    const int w    = tid >> 6;
    const int ml   = lane & 15;
    const int kg   = lane >> 4;

    f32x4 acc[4];
    #pragma unroll
    for (int ft = 0; ft < 4; ++ft) { f32x4 z = {0.f,0.f,0.f,0.f}; acc[ft] = z; }
    #pragma unroll
    for (int ft = 0; ft < 4; ++ft)
        #pragma unroll
        for (int kit = 0; kit < 4; ++kit) {
            half8 af = *(const half8*)&sv[(w * 16 + ml) * 136 + kit * 32 + kg * 8];
            half8 bf = *(const half8*)&sk[(ft * 16 + ml) * 136 + kit * 32 + kg * 8];
            acc[ft] = __builtin_amdgcn_mfma_f32_16x16x32_f16(af, bf, acc[ft], 0, 0, 0);
        }
    float* o = kvT + (size_t)blk * 4096;
    #pragma unroll
    for (int ft = 0; ft < 4; ++ft)
        #pragma unroll
        for (int t = 0; t < 4; ++t) {
            int e = w * 16 + kg * 4 + t;
            o[e * 64 + ft * 16 + ml] = acc[ft][t];
        }
}

// ---------------------------------------------------------------------------
// Exclusive cumsum over chunk axis. 1024 blocks: bh = blk>>4, seg = blk&15.
// ---------------------------------------------------------------------------
__global__ __launch_bounds__(256) void scan_chunks(float* __restrict__ kvT,
                                                   float* __restrict__ ksum) {
    const int bh  = blockIdx.x >> 4;
    const int seg = blockIdx.x & 15;
    const int idx = seg * 256 + threadIdx.x;
    float* base = kvT + (size_t)bh * NCHUNK * 4096 + idx;
    float run = 0.f;
    #pragma unroll
    for (int nn = 0; nn < NCHUNK; ++nn) {
        float t = base[(size_t)nn * 4096];
        base[(size_t)nn * 4096] = run;
        run += t;
    }
    if (seg == 0 && threadIdx.x < 64) {
        float* zb = ksum + (size_t)bh * NCHUNK * 64 + threadIdx.x;
        float r2 = 0.f;
        #pragma unroll
        for (int nn = 0; nn < NCHUNK; ++nn) {
            float t = zb[nn * 64];
            zb[nn * 64] = r2;
            r2 += t;
        }
    }
}

// ---------------------------------------------------------------------------
// MFMA attention core with FUSED fp32-grade denominator (unchanged).
// ---------------------------------------------------------------------------
__global__ __launch_bounds__(256) void attn_core(
    const _Float16* __restrict__ q16g, const _Float16* __restrict__ k16g,
    const _Float16* __restrict__ v16g, const _Float16* __restrict__ qlog,
    const _Float16* __restrict__ klog, const float* __restrict__ STg,
    const float* __restrict__ zg, _Float16* __restrict__ O16) {
    const int blk = blockIdx.x;
    const int n = blk & 15, bh = blk >> 4, h = bh & 15, b = bh >> 4;
    const size_t base = ((size_t)b * L_SEQ + (size_t)n * CHUNK) * D_MODEL + (size_t)h * HDIM;

    __shared__ __align__(16) _Float16 sq [128 * 72];
    __shared__ __align__(16) _Float16 sk [128 * 72];
    __shared__ __align__(16) _Float16 sv [64 * 136];
    __shared__ __align__(16) _Float16 sS [64 * 72];
    __shared__ __align__(16) _Float16 ssc[64 * 136];
    __shared__ float szz[64];

    const int tid = threadIdx.x;
    #pragma unroll
    for (int p = 0; p < 4; ++p) {
        int idx = p * 256 + tid;
        int j = idx >> 3, c = idx & 7;
        *(half8*)&sq[j * 72 + c * 8] = *(const half8*)(q16g + base + (size_t)j * D_MODEL + c * 8);
        *(half8*)&sk[j * 72 + c * 8] = *(const half8*)(k16g + base + (size_t)j * D_MODEL + c * 8);
        half8 vv = *(const half8*)(v16g + base + (size_t)j * D_MODEL + c * 8);
        #pragma unroll
        for (int u = 0; u < 8; ++u) sv[(c * 8 + u) * 136 + j] = vv[u];
    }
    #pragma unroll
    for (int p = 0; p < 2; ++p) {
        int idx = p * 256 + tid;
        int e = idx >> 3, c = idx & 7;
        f32x4 a = *(const f32x4*)(STg + (size_t)blk * 4096 + e * 64 + c * 8);
        f32x4 b4 = *(const f32x4*)(STg + (size_t)blk * 4096 + e * 64 + c * 8 + 4);
        half8 hv;
        hv[0] = (_Float16)a.x;  hv[1] = (_Float16)a.y;
        hv[2] = (_Float16)a.z;  hv[3] = (_Float16)a.w;
        hv[4] = (_Float16)b4.x; hv[5] = (_Float16)b4.y;
        hv[6] = (_Float16)b4.z; hv[7] = (_Float16)b4.w;
        *(half8*)&sS[e * 72 + c * 8] = hv;
    }
    if (tid < 64) szz[tid] = zg[(size_t)blk * 64 + tid];
    __syncthreads();

    const int lane = tid & 63;
    const int w    = tid >> 6;
    const int ml   = lane & 15;
    const int kg   = lane >> 4;

    for (int h2 = 0; h2 < 2; ++h2) {
        const int r0 = h2 * 64 + w * 16;
        const int rowmax = r0 + 15;

        half8 aflo[2];
        aflo[0] = *(const half8*)(qlog + base + (size_t)(r0 + ml) * D_MODEL + kg * 8);
        aflo[1] = *(const half8*)(qlog + base + (size_t)(r0 + ml) * D_MODEL + 32 + kg * 8);

        f32x4 acc1[8];
        #pragma unroll
        for (int nt = 0; nt < 8; ++nt) { f32x4 z = {0.f,0.f,0.f,0.f}; acc1[nt] = z; }
        #pragma unroll
        for (int nt = 0; nt < 8; ++nt) {
            if (nt * 16 <= rowmax) {
                #pragma unroll
                for (int kit = 0; kit < 2; ++kit) {
                    half8 af = *(const half8*)&sq[(r0 + ml) * 72 + kit * 32 + kg * 8];
                    half8 bf = *(const half8*)&sk[(nt * 16 + ml) * 72 + kit * 32 + kg * 8];
                    acc1[nt] = __builtin_amdgcn_mfma_f32_16x16x32_f16(af, bf, acc1[nt], 0, 0, 0);
                }
            }
        }
        #pragma unroll
        for (int nt = 0; nt < 8; ++nt) {
            if (nt * 16 <= rowmax) {
                const _Float16* kb = klog + base + (size_t)(nt * 16 + ml) * D_MODEL;
                half8 bl0 = *(const half8*)(kb + kg * 8);
                half8 bl1 = *(const half8*)(kb + 32 + kg * 8);
                half8 ah0 = *(const half8*)&sq[(r0 + ml) * 72 + kg * 8];
                half8 ah1 = *(const half8*)&sq[(r0 + ml) * 72 + 32 + kg * 8];
                half8 bh0 = *(const half8*)&sk[(nt * 16 + ml) * 72 + kg * 8];
                half8 bh1 = *(const half8*)&sk[(nt * 16 + ml) * 72 + 32 + kg * 8];
                acc1[nt] = __builtin_amdgcn_mfma_f32_16x16x32_f16(ah0, bl0, acc1[nt], 0, 0, 0);
                acc1[nt] = __builtin_amdgcn_mfma_f32_16x16x32_f16(ah1, bl1, acc1[nt], 0, 0, 0);
                acc1[nt] = __builtin_amdgcn_mfma_f32_16x16x32_f16(aflo[0], bh0, acc1[nt], 0, 0, 0);
                acc1[nt] = __builtin_amdgcn_mfma_f32_16x16x32_f16(aflo[1], bh1, acc1[nt], 0, 0, 0);
            }
        }

        float rs[4];
        #pragma unroll
        for (int t = 0; t < 4; ++t) {
            const int ig = r0 + kg * 4 + t;
            float s = 0.f;
            #pragma unroll
            for (int nt = 0; nt < 8; ++nt) {
                int jg = nt * 16 + ml;
                s += (jg <= ig) ? acc1[nt][t] : 0.f;
            }
            const int f0 = ml * 4;
            half4 ql = *(const half4*)(qlog + base + (size_t)ig * D_MODEL + f0);
            #pragma unroll
            for (int u = 0; u < 4; ++u)
                s += ((float)sq[ig * 72 + f0 + u] + (float)ql[u]) * szz[f0 + u];
            s += __shfl_xor(s, 1, 64);
            s += __shfl_xor(s, 2, 64);
            s += __shfl_xor(s, 4, 64);
            s += __shfl_xor(s, 8, 64);
            rs[t] = s;
        }

        #pragma unroll
        for (int nt = 0; nt < 8; ++nt) {
            #pragma unroll
            for (int t = 0; t < 4; ++t) {
                int lr = w * 16 + kg * 4 + t;
                int ig = h2 * 64 + lr;
                int jg = nt * 16 + ml;
                float val = (jg <= ig) ? acc1[nt][t] : 0.f;
                ssc[lr * 136 + jg] = (_Float16)val;
            }
        }
        __syncthreads();

        f32x4 acc2[4];
        #pragma unroll
        for (int et = 0; et < 4; ++et) { f32x4 z = {0.f,0.f,0.f,0.f}; acc2[et] = z; }
        const int nkit = (h2 == 0) ? 2 : 4;
        #pragma unroll
        for (int et = 0; et < 4; ++et) {
            for (int kit = 0; kit < nkit; ++kit) {
                half8 af = *(const half8*)&ssc[(w * 16 + ml) * 136 + kit * 32 + kg * 8];
                half8 bf = *(const half8*)&sv[(et * 16 + ml) * 136 + kit * 32 + kg * 8];
                acc2[et] = __builtin_amdgcn_mfma_f32_16x16x32_f16(af, bf, acc2[et], 0, 0, 0);
            }
            #pragma unroll
            for (int kit = 0; kit < 2; ++kit) {
                half8 af = *(const half8*)&sq[(r0 + ml) * 72 + kit * 32 + kg * 8];
                half8 bf = *(const half8*)&sS[(et * 16 + ml) * 72 + kit * 32 + kg * 8];
                acc2[et] = __builtin_amdgcn_mfma_f32_16x16x32_f16(af, bf, acc2[et], 0, 0, 0);
            }
        }
        #pragma unroll
        for (int t = 0; t < 4; ++t) {
            int lr = w * 16 + kg * 4 + t;
            int ig = h2 * 64 + lr;
            float rc = 0.015625f / fmaxf(rs[t], EPS_DEN);
            #pragma unroll
            for (int et = 0; et < 4; ++et) {
                int e = et * 16 + ml;
                O16[base + (size_t)ig * D_MODEL + e] = (_Float16)(acc2[et][t] * rc);
            }
        }
        __syncthreads();
    }
}

// ---------------------------------------------------------------------------
extern "C" void kernel_launch(void* const* d_in, const int* in_sizes, int n_in,
                              void* d_out, int out_size, void* d_ws, size_t ws_size,
                              hipStream_t stream) {
    const float* x  = (const float*)d_in[0];
    const float* Wq = (const float*)d_in[1];
    const float* bq = (const float*)d_in[2];
    const float* Wk = (const float*)d_in[3];
    const float* bk = (const float*)d_in[4];
    const float* Wv = (const float*)d_in[5];
    const float* bv = (const float*)d_in[6];
    const float* Wo = (const float*)d_in[7];
    const float* bo = (const float*)d_in[8];
    float* out = (float*)d_out;

    char* p = (char*)d_ws;
    _Float16* x2   = (_Float16*)p;  p += (size_t)NTOK * 2048 * 2;
    _Float16* w2q  = (_Float16*)p;  p += (size_t)1024 * 2048 * 2;
    _Float16* w2k  = (_Float16*)p;  p += (size_t)1024 * 2048 * 2;   // contiguous after w2q
    _Float16* wv16 = (_Float16*)p;  p += (size_t)1024 * 1024 * 2;
    _Float16* wo16 = (_Float16*)p;  p += (size_t)1024 * 1024 * 2;
    _Float16* qlo  = (_Float16*)p;  p += (size_t)NTOK * 1024 * 2;
    _Float16* klo  = (_Float16*)p;  p += (size_t)NTOK * 1024 * 2;
    _Float16* q16  = (_Float16*)p;  p += (size_t)NTOK * 1024 * 2;
    _Float16* k16  = (_Float16*)p;  p += (size_t)NTOK * 1024 * 2;
    _Float16* v16  = (_Float16*)p;  p += (size_t)NTOK * 1024 * 2;
    float* kvT  = (float*)p;        p += (size_t)1024 * 4096 * 4;
    float* ksb  = (float*)p;        p += (size_t)1024 * 64 * 4;
    float* bqk  = (float*)p;        p += 2048 * 4;
    _Float16* attn16 = x2;  // x2 dead after gemm_qkv

    prep<<<6152, 256, 0, stream>>>(x, Wq, Wk, Wv, Wo, bq, bk,
                                   x2, w2q, w2k, wv16, wo16, bqk);

    gemm_qkv<<<dim3(32, 8), 512, 0, stream>>>(x2, w2q, wv16, bqk, bv,
                                              qlo, klo, q16, k16, v16, ksb);

    chunk_stats<<<1024, 256, 0, stream>>>(k16, v16, kvT);
    scan_chunks<<<1024, 256, 0, stream>>>(kvT, ksb);
    attn_core<<<1024, 256, 0, stream>>>(q16, k16, v16, qlo, klo, kvT, ksb, attn16);

    gemm_out<<<dim3(64, 8), 256, 0, stream>>>(attn16, wo16, bo, out);
}

// Round 5
// 338.586 us; speedup vs baseline: 1.0507x; 1.0507x over previous
//
#include <hip/hip_runtime.h>
#include <math.h>

#define D_MODEL 1024
#define HEADS   16
#define HDIM    64
#define CHUNK   128
#define B_SZ    4
#define L_SEQ   2048
#define NCHUNK  16
#define NTOK    8192
#define EPS_DEN 1e-3f

typedef _Float16 half8 __attribute__((ext_vector_type(8)));
typedef _Float16 half4 __attribute__((ext_vector_type(4)));
typedef float    f32x4 __attribute__((ext_vector_type(4)));

__device__ __forceinline__ void gld_lds16(const void* g, void* l) {
    __builtin_amdgcn_global_load_lds(
        (const __attribute__((address_space(1))) void*)g,
        (__attribute__((address_space(3))) void*)l, 16, 0, 0);
}

// ---------------------------------------------------------------------------
// Fused preprocessing: x->hi|lo, Wq->hi|lo, Wk->hi|lo, Wv->f16, Wo->f16,
// bias concat [bq|bk].
// ---------------------------------------------------------------------------
__global__ __launch_bounds__(256) void prep(
    const float* __restrict__ x,  const float* __restrict__ Wq,
    const float* __restrict__ Wk, const float* __restrict__ Wv,
    const float* __restrict__ Wo, const float* __restrict__ bq,
    const float* __restrict__ bk,
    _Float16* __restrict__ x2,  _Float16* __restrict__ w2q,
    _Float16* __restrict__ w2k, _Float16* __restrict__ wv16,
    _Float16* __restrict__ wo16, float* __restrict__ bqk) {
    const int bid = blockIdx.x;
    if (bid < 5120) {           // split jobs: x / Wq / Wk
        const float* src; _Float16* dst; int t;
        if (bid < 4096)      { src = x;  dst = x2;  t = bid * 256 + threadIdx.x; }
        else if (bid < 4608) { src = Wq; dst = w2q; t = (bid - 4096) * 256 + threadIdx.x; }
        else                 { src = Wk; dst = w2k; t = (bid - 4608) * 256 + threadIdx.x; }
        int m = t >> 7, kc = (t & 127) << 3;
        const float* s = src + (size_t)m * 1024 + kc;
        f32x4 a = *(const f32x4*)s;
        f32x4 b = *(const f32x4*)(s + 4);
        float xs[8] = {a.x, a.y, a.z, a.w, b.x, b.y, b.z, b.w};
        half8 hi, lo;
        #pragma unroll
        for (int u = 0; u < 8; ++u) {
            _Float16 h = (_Float16)xs[u];
            hi[u] = h;
            lo[u] = (_Float16)(xs[u] - (float)h);
        }
        *(half8*)(dst + (size_t)m * 2048 + kc)        = hi;
        *(half8*)(dst + (size_t)m * 2048 + 1024 + kc) = lo;
    } else if (bid < 6144) {    // conv jobs: Wv / Wo
        const float* src; _Float16* dst; int t;
        if (bid < 5632) { src = Wv; dst = wv16; t = (bid - 5120) * 256 + threadIdx.x; }
        else            { src = Wo; dst = wo16; t = (bid - 5632) * 256 + threadIdx.x; }
        int m = t >> 7, kc = (t & 127) << 3;
        const float* s = src + (size_t)m * 1024 + kc;
        f32x4 a = *(const f32x4*)s;
        f32x4 b = *(const f32x4*)(s + 4);
        float xs[8] = {a.x, a.y, a.z, a.w, b.x, b.y, b.z, b.w};
        half8 hv;
        #pragma unroll
        for (int u = 0; u < 8; ++u) hv[u] = (_Float16)xs[u];
        *(half8*)(dst + (size_t)m * 1024 + kc) = hv;
    } else {
        int i = (bid - 6144) * 256 + threadIdx.x;
        bqk[i] = (i < 1024) ? bq[i] : bk[i - 1024];
    }
}

// ---------------------------------------------------------------------------
// Fused q/k/v projection GEMM. Round-0 geometry (128x128 tile, 4 waves,
// grid dim3(64,24), 4 blocks/CU) + catalog "minimum 2-phase" double buffer
// (T3 recipe, m248v2: 1.10x over 2-barrier at equal occupancy):
//   stage(t+1 -> buf^1) issued BEFORE ds_read+MFMA of buf  (latency cover)
//   one vmcnt(0)+barrier per K-step (not two barriers)
// Race: stage overwrites data whose ds_reads completed before the previous
// iteration's barrier (MFMA data-dependence); stage issues after it. Safe.
// cb 0..15 : q/k split GEMM, K=3072 logical [hi*hi|lo*hi|hi*lo], silu,
//            f16 LO-residual direct stores + f16 hi slab stores.
//            k-blocks also emit fused ksum (fp32).
// cb 16..23: v plain f16 GEMM, K=1024 (hi half of x2), f16 slab only.
// ---------------------------------------------------------------------------
__global__ __launch_bounds__(256, 4) void gemm_qkv(
    const _Float16* __restrict__ A,    // x2, lda 2048
    const _Float16* __restrict__ Bqk,  // [w2q;w2k], ldb 2048
    const _Float16* __restrict__ Bv,   // wv16, ldb 1024
    const float* __restrict__ bqk, const float* __restrict__ bv,
    _Float16* __restrict__ Qlo, _Float16* __restrict__ Klo,
    _Float16* __restrict__ Q16, _Float16* __restrict__ K16,
    _Float16* __restrict__ V16, float* __restrict__ ksum) {
    // two buffers of [A 128x32 | B 128x32] = 16KB each; slab reuses sbuf.
    __shared__ __align__(16) _Float16 sbuf[2 * 8192];
    __shared__ float sksum[2][128];
    _Float16* sC16 = sbuf;              // epilogue slab (needs 4352h <= 8192h)

    const int cb   = blockIdx.y;
    const int isqk = (cb < 16);
    const int isk  = (cb >= 8 && cb < 16);
    const int tid  = threadIdx.x;
    const int lane = tid & 63;
    const int w    = tid >> 6;
    const int row0 = blockIdx.x * 128;
    const int col0 = cb * 128;               // 0..3071 global col space
    const int wm   = (w & 1) * 64;
    const int wn   = (w >> 1) * 64;

    const _Float16* B = isqk ? Bqk : Bv;
    const int ldb     = isqk ? 2048 : 1024;
    const int bcol0   = isqk ? col0 : col0 - 2048;
    const int kits    = isqk ? 96 : 32;

    const int ch0 = w * 64 + lane;
    const int rS0 = ch0 >> 2;
    const int cS0 = (ch0 & 3) ^ ((rS0 >> 1) & 3);
    const int ch1 = ch0 + 256;
    const int rS1 = ch1 >> 2;
    const int cS1 = (ch1 & 3) ^ ((rS1 >> 1) & 3);

    const _Float16* gA0 = A + (size_t)(row0  + rS0) * 2048 + cS0 * 8;
    const _Float16* gA1 = A + (size_t)(row0  + rS1) * 2048 + cS1 * 8;
    const _Float16* gB0 = B + (size_t)(bcol0 + rS0) * ldb  + cS0 * 8;
    const _Float16* gB1 = B + (size_t)(bcol0 + rS1) * ldb  + cS1 * 8;

    auto stage = [&](int kt, int bsel) {
        const int k0   = kt * 32;
        const int acol = (k0 < 2048) ? k0 : k0 - 2048;
        const int bcol = (k0 < 1024) ? k0 : k0 - 1024;
        _Float16* l = sbuf + bsel * 8192;
        gld_lds16(gA0 + acol, l + w * 512);
        gld_lds16(gA1 + acol, l + 2048 + w * 512);
        gld_lds16(gB0 + bcol, l + 4096 + w * 512);
        gld_lds16(gB1 + bcol, l + 6144 + w * 512);
    };

    f32x4 acc[4][4];
    #pragma unroll
    for (int i = 0; i < 4; ++i)
        #pragma unroll
        for (int j = 0; j < 4; ++j) { f32x4 z = {0.f, 0.f, 0.f, 0.f}; acc[i][j] = z; }

    const int ml = lane & 15;
    const int kg = lane >> 4;
    int offA[4], offB[4];
    #pragma unroll
    for (int i = 0; i < 4; ++i) {
        int r  = wm + i * 16 + ml;
        offA[i] = r * 32 + (kg ^ ((r >> 1) & 3)) * 8;
        int rn = wn + i * 16 + ml;
        offB[i] = 4096 + rn * 32 + (kg ^ ((rn >> 1) & 3)) * 8;
    }

    stage(0, 0);
    asm volatile("s_waitcnt vmcnt(0)\n\ts_barrier" ::: "memory");
    int cur = 0;
    for (int t = 0; t < kits; ++t) {
        if (t + 1 < kits) stage(t + 1, cur ^ 1);   // issue BEFORE compute
        const _Float16* lb = sbuf + cur * 8192;
        half8 af[4], bf[4];
        #pragma unroll
        for (int i = 0; i < 4; ++i) {
            af[i] = *(const half8*)&lb[offA[i]];
            bf[i] = *(const half8*)&lb[offB[i]];
        }
        __builtin_amdgcn_s_setprio(1);
        #pragma unroll
        for (int i = 0; i < 4; ++i)
            #pragma unroll
            for (int j = 0; j < 4; ++j)
                acc[i][j] = __builtin_amdgcn_mfma_f32_16x16x32_f16(af[i], bf[j], acc[i][j], 0, 0, 0);
        __builtin_amdgcn_s_setprio(0);
        asm volatile("s_waitcnt vmcnt(0)\n\ts_barrier" ::: "memory");
        cur ^= 1;
    }

    // output routing
    const int colq = isqk ? ((col0 < 1024) ? col0 : col0 - 1024) : (col0 - 2048);
    _Float16* Ylo  = (col0 < 1024) ? Qlo : Klo;      // only used when isqk
    _Float16* Y16  = isqk ? ((col0 < 1024) ? Q16 : K16) : V16;

    const int rg = lane >> 4;
    #pragma unroll
    for (int j = 0; j < 4; ++j) {
        const float bvb = isqk ? bqk[col0 + wn + j * 16 + ml]
                               : bv[colq + wn + j * 16 + ml];
        const int nn = colq + wn + j * 16 + ml;
        #pragma unroll
        for (int i = 0; i < 4; ++i) {
            #pragma unroll
            for (int t = 0; t < 4; ++t) {
                float vv = acc[i][j][t] + bvb;
                if (isqk) {
                    vv = vv / (1.f + expf(-vv));     // silu
                    int mm = row0 + wm + i * 16 + rg * 4 + t;
                    _Float16 hv = (_Float16)vv;      // hi (same cast as slab)
                    Ylo[(size_t)mm * 1024 + nn] = (_Float16)(vv - (float)hv);
                }
                acc[i][j][t] = vv;
            }
        }
    }

    // fused ksum for k-blocks: this tile = chunk (b,n) x 2 heads.
    if (isk) {
        #pragma unroll
        for (int j = 0; j < 4; ++j) {
            float ps = 0.f;
            #pragma unroll
            for (int i = 0; i < 4; ++i)
                #pragma unroll
                for (int t = 0; t < 4; ++t) ps += acc[i][j][t];
            // reduce over the 4 rg lane groups (lanes kg*16+ml)
            ps += __shfl_xor(ps, 16, 64);
            ps += __shfl_xor(ps, 32, 64);
            if (kg == 0) sksum[wm >> 6][wn + j * 16 + ml] = ps;
        }
        __syncthreads();
        if (tid < 128) {
            const int b = row0 >> 11;
            const int n = (row0 >> 7) & 15;
            const int cg = colq + tid;         // global k-col
            const int h = cg >> 6, f = cg & 63;
            ksum[(size_t)(((b * 16 + h) * 16 + n)) * 64 + f] =
                sksum[0][tid] + sksum[1][tid];
        }
        __syncthreads();
    }

    // f16 via LDS slab transpose (4 slabs of 32 rows), slab buffer = sbuf
    for (int s = 0; s < 4; ++s) {
        if ((wm == 0) == (s < 2)) {
            const int ib = (s & 1) * 2;
            #pragma unroll
            for (int ii = 0; ii < 2; ++ii)
                #pragma unroll
                for (int j = 0; j < 4; ++j)
                    #pragma unroll
                    for (int t = 0; t < 4; ++t) {
                        int lr = ii * 16 + rg * 4 + t;
                        sC16[lr * 136 + wn + j * 16 + ml] = (_Float16)acc[ib + ii][j][t];
                    }
        }
        __syncthreads();
        #pragma unroll
        for (int u = 0; u < 2; ++u) {
            int c = u * 256 + tid;
            int r = c >> 4, cc = (c & 15) * 8;
            half8 hv = *(const half8*)&sC16[r * 136 + cc];
            *(half8*)(Y16 + (size_t)(row0 + 32 * s + r) * 1024 + colq + cc) = hv;
        }
        __syncthreads();
    }
}

// ---------------------------------------------------------------------------
// Final output GEMM: out = attn16 * wo16^T * 64 + bo. Tile 128x128, BK=32,
// catalog 2-phase double buffer (same as gemm_qkv). grid dim3(64, 8).
// ---------------------------------------------------------------------------
__global__ __launch_bounds__(256, 4) void gemm_out(
    const _Float16* __restrict__ A,   // attn16, lda 1024
    const _Float16* __restrict__ B,   // wo16, ldb 1024
    const float* __restrict__ bias,
    float* __restrict__ Y) {
    __shared__ __align__(16) _Float16 sbuf[2 * 8192];  // [A 128x32 | B 128x32] x2

    const int tid  = threadIdx.x;
    const int lane = tid & 63;
    const int w    = tid >> 6;
    const int row0 = blockIdx.x * 128;
    const int col0 = blockIdx.y * 128;
    const int wm   = (w & 1) * 64;
    const int wn   = (w >> 1) * 64;

    const int ch0 = w * 64 + lane;
    const int rS0 = ch0 >> 2;
    const int cS0 = (ch0 & 3) ^ ((rS0 >> 1) & 3);
    const int ch1 = ch0 + 256;
    const int rS1 = ch1 >> 2;
    const int cS1 = (ch1 & 3) ^ ((rS1 >> 1) & 3);

    const _Float16* gA0 = A + (size_t)(row0 + rS0) * 1024 + cS0 * 8;
    const _Float16* gA1 = A + (size_t)(row0 + rS1) * 1024 + cS1 * 8;
    const _Float16* gB0 = B + (size_t)(col0 + rS0) * 1024 + cS0 * 8;
    const _Float16* gB1 = B + (size_t)(col0 + rS1) * 1024 + cS1 * 8;

    auto stage = [&](int kt, int bsel) {
        const int k0 = kt * 32;
        _Float16* l = sbuf + bsel * 8192;
        gld_lds16(gA0 + k0, l + w * 512);
        gld_lds16(gA1 + k0, l + 2048 + w * 512);
        gld_lds16(gB0 + k0, l + 4096 + w * 512);
        gld_lds16(gB1 + k0, l + 6144 + w * 512);
    };

    f32x4 acc[4][4];
    #pragma unroll
    for (int i = 0; i < 4; ++i)
        #pragma unroll
        for (int j = 0; j < 4; ++j) { f32x4 z = {0.f, 0.f, 0.f, 0.f}; acc[i][j] = z; }

    const int ml = lane & 15;
    const int kg = lane >> 4;
    int offA[4], offB[4];
    #pragma unroll
    for (int i = 0; i < 4; ++i) {
        int r  = wm + i * 16 + ml;
        offA[i] = r * 32 + (kg ^ ((r >> 1) & 3)) * 8;
        int rn = wn + i * 16 + ml;
        offB[i] = 4096 + rn * 32 + (kg ^ ((rn >> 1) & 3)) * 8;
    }

    stage(0, 0);
    asm volatile("s_waitcnt vmcnt(0)\n\ts_barrier" ::: "memory");
    int cur = 0;
    for (int kit = 0; kit < 32; ++kit) {
        if (kit + 1 < 32) stage(kit + 1, cur ^ 1);
        const _Float16* lb = sbuf + cur * 8192;
        half8 af[4], bf[4];
        #pragma unroll
        for (int i = 0; i < 4; ++i) {
            af[i] = *(const half8*)&lb[offA[i]];
            bf[i] = *(const half8*)&lb[offB[i]];
        }
        __builtin_amdgcn_s_setprio(1);
        #pragma unroll
        for (int i = 0; i < 4; ++i)
            #pragma unroll
            for (int j = 0; j < 4; ++j)
                acc[i][j] = __builtin_amdgcn_mfma_f32_16x16x32_f16(af[i], bf[j], acc[i][j], 0, 0, 0);
        __builtin_amdgcn_s_setprio(0);
        asm volatile("s_waitcnt vmcnt(0)\n\ts_barrier" ::: "memory");
        cur ^= 1;
    }

    const int rg = lane >> 4;
    #pragma unroll
    for (int j = 0; j < 4; ++j) {
        const int nn = col0 + wn + j * 16 + ml;
        const float bvb = bias[nn];
        #pragma unroll
        for (int i = 0; i < 4; ++i) {
            #pragma unroll
            for (int t = 0; t < 4; ++t) {
                int mm = row0 + wm + i * 16 + rg * 4 + t;
                Y[(size_t)mm * 1024 + nn] = acc[i][j][t] * 64.f + bvb;
            }
        }
    }
}

// ---------------------------------------------------------------------------
// chunk stats: kvT[blk][e][f] = sum_j v16[j][e]*k16[j][f] via MFMA.
// ---------------------------------------------------------------------------
__global__ __launch_bounds__(256) void chunk_stats(
    const _Float16* __restrict__ k16g, const _Float16* __restrict__ v16g,
    float* __restrict__ kvT) {
    const int blk = blockIdx.x;
    const int n = blk & 15, bh = blk >> 4, h = bh & 15, b = bh >> 4;
    const size_t base = ((size_t)b * L_SEQ + (size_t)n * CHUNK) * D_MODEL + (size_t)h * HDIM;

    __shared__ __align__(16) _Float16 sv[64 * 136];
    __shared__ __align__(16) _Float16 sk[64 * 136];

    const int tid = threadIdx.x;
    #pragma unroll
    for (int p = 0; p < 4; ++p) {
        int idx = p * 256 + tid;
        int j = idx >> 3, c = idx & 7;
        half8 vv = *(const half8*)(v16g + base + (size_t)j * D_MODEL + c * 8);
        half8 kk = *(const half8*)(k16g + base + (size_t)j * D_MODEL + c * 8);
        #pragma unroll
        for (int u = 0; u < 8; ++u) {
            sv[(c * 8 + u) * 136 + j] = vv[u];
            sk[(c * 8 + u) * 136 + j] = kk[u];
        }
    }
    __syncthreads();

    const int lane = tid & 63;
    const int w    = tid >> 6;
    const int ml   = lane & 15;
    const int kg   = lane >> 4;

    f32x4 acc[4];
    #pragma unroll
    for (int ft = 0; ft < 4; ++ft) { f32x4 z = {0.f,0.f,0.f,0.f}; acc[ft] = z; }
    #pragma unroll
    for (int ft = 0; ft < 4; ++ft)
        #pragma unroll
        for (int kit = 0; kit < 4; ++kit) {
            half8 af = *(const half8*)&sv[(w * 16 + ml) * 136 + kit * 32 + kg * 8];
            half8 bf = *(const half8*)&sk[(ft * 16 + ml) * 136 + kit * 32 + kg * 8];
            acc[ft] = __builtin_amdgcn_mfma_f32_16x16x32_f16(af, bf, acc[ft], 0, 0, 0);
        }
    float* o = kvT + (size_t)blk * 4096;
    #pragma unroll
    for (int ft = 0; ft < 4; ++ft)
        #pragma unroll
        for (int t = 0; t < 4; ++t) {
            int e = w * 16 + kg * 4 + t;
            o[e * 64 + ft * 16 + ml] = acc[ft][t];
        }
}

// ---------------------------------------------------------------------------
// Exclusive cumsum over chunk axis. 1024 blocks: bh = blk>>4, seg = blk&15.
// ---------------------------------------------------------------------------
__global__ __launch_bounds__(256) void scan_chunks(float* __restrict__ kvT,
                                                   float* __restrict__ ksum) {
    const int bh  = blockIdx.x >> 4;
    const int seg = blockIdx.x & 15;
    const int idx = seg * 256 + threadIdx.x;
    float* base = kvT + (size_t)bh * NCHUNK * 4096 + idx;
    float run = 0.f;
    #pragma unroll
    for (int nn = 0; nn < NCHUNK; ++nn) {
        float t = base[(size_t)nn * 4096];
        base[(size_t)nn * 4096] = run;
        run += t;
    }
    if (seg == 0 && threadIdx.x < 64) {
        float* zb = ksum + (size_t)bh * NCHUNK * 64 + threadIdx.x;
        float r2 = 0.f;
        #pragma unroll
        for (int nn = 0; nn < NCHUNK; ++nn) {
            float t = zb[nn * 64];
            zb[nn * 64] = r2;
            r2 += t;
        }
    }
}

// ---------------------------------------------------------------------------
// MFMA attention core with FUSED fp32-grade denominator (unchanged from R3).
// ---------------------------------------------------------------------------
__global__ __launch_bounds__(256) void attn_core(
    const _Float16* __restrict__ q16g, const _Float16* __restrict__ k16g,
    const _Float16* __restrict__ v16g, const _Float16* __restrict__ qlog,
    const _Float16* __restrict__ klog, const float* __restrict__ STg,
    const float* __restrict__ zg, _Float16* __restrict__ O16) {
    const int blk = blockIdx.x;
    const int n = blk & 15, bh = blk >> 4, h = bh & 15, b = bh >> 4;
    const size_t base = ((size_t)b * L_SEQ + (size_t)n * CHUNK) * D_MODEL + (size_t)h * HDIM;

    __shared__ __align__(16) _Float16 sq [128 * 72];
    __shared__ __align__(16) _Float16 sk [128 * 72];
    __shared__ __align__(16) _Float16 sv [64 * 136];
    __shared__ __align__(16) _Float16 sS [64 * 72];
    __shared__ __align__(16) _Float16 ssc[64 * 136];
    __shared__ float szz[64];

    const int tid = threadIdx.x;
    #pragma unroll
    for (int p = 0; p < 4; ++p) {
        int idx = p * 256 + tid;
        int j = idx >> 3, c = idx & 7;
        *(half8*)&sq[j * 72 + c * 8] = *(const half8*)(q16g + base + (size_t)j * D_MODEL + c * 8);
        *(half8*)&sk[j * 72 + c * 8] = *(const half8*)(k16g + base + (size_t)j * D_MODEL + c * 8);
        half8 vv = *(const half8*)(v16g + base + (size_t)j * D_MODEL + c * 8);
        #pragma unroll
        for (int u = 0; u < 8; ++u) sv[(c * 8 + u) * 136 + j] = vv[u];
    }
    #pragma unroll
    for (int p = 0; p < 2; ++p) {
        int idx = p * 256 + tid;
        int e = idx >> 3, c = idx & 7;
        f32x4 a = *(const f32x4*)(STg + (size_t)blk * 4096 + e * 64 + c * 8);
        f32x4 b4 = *(const f32x4*)(STg + (size_t)blk * 4096 + e * 64 + c * 8 + 4);
        half8 hv;
        hv[0] = (_Float16)a.x;  hv[1] = (_Float16)a.y;
        hv[2] = (_Float16)a.z;  hv[3] = (_Float16)a.w;
        hv[4] = (_Float16)b4.x; hv[5] = (_Float16)b4.y;
        hv[6] = (_Float16)b4.z; hv[7] = (_Float16)b4.w;
        *(half8*)&sS[e * 72 + c * 8] = hv;
    }
    if (tid < 64) szz[tid] = zg[(size_t)blk * 64 + tid];
    __syncthreads();

    const int lane = tid & 63;
    const int w    = tid >> 6;
    const int ml   = lane & 15;
    const int kg   = lane >> 4;

    for (int h2 = 0; h2 < 2; ++h2) {
        const int r0 = h2 * 64 + w * 16;
        const int rowmax = r0 + 15;

        half8 aflo[2];
        aflo[0] = *(const half8*)(qlog + base + (size_t)(r0 + ml) * D_MODEL + kg * 8);
        aflo[1] = *(const half8*)(qlog + base + (size_t)(r0 + ml) * D_MODEL + 32 + kg * 8);

        f32x4 acc1[8];
        #pragma unroll
        for (int nt = 0; nt < 8; ++nt) { f32x4 z = {0.f,0.f,0.f,0.f}; acc1[nt] = z; }
        #pragma unroll
        for (int nt = 0; nt < 8; ++nt) {
            if (nt * 16 <= rowmax) {
                #pragma unroll
                for (int kit = 0; kit < 2; ++kit) {
                    half8 af = *(const half8*)&sq[(r0 + ml) * 72 + kit * 32 + kg * 8];
                    half8 bf = *(const half8*)&sk[(nt * 16 + ml) * 72 + kit * 32 + kg * 8];
                    acc1[nt] = __builtin_amdgcn_mfma_f32_16x16x32_f16(af, bf, acc1[nt], 0, 0, 0);
                }
            }
        }
        #pragma unroll
        for (int nt = 0; nt < 8; ++nt) {
            if (nt * 16 <= rowmax) {
                const _Float16* kb = klog + base + (size_t)(nt * 16 + ml) * D_MODEL;
                half8 bl0 = *(const half8*)(kb + kg * 8);
                half8 bl1 = *(const half8*)(kb + 32 + kg * 8);
                half8 ah0 = *(const half8*)&sq[(r0 + ml) * 72 + kg * 8];
                half8 ah1 = *(const half8*)&sq[(r0 + ml) * 72 + 32 + kg * 8];
                half8 bh0 = *(const half8*)&sk[(nt * 16 + ml) * 72 + kg * 8];
                half8 bh1 = *(const half8*)&sk[(nt * 16 + ml) * 72 + 32 + kg * 8];
                acc1[nt] = __builtin_amdgcn_mfma_f32_16x16x32_f16(ah0, bl0, acc1[nt], 0, 0, 0);
                acc1[nt] = __builtin_amdgcn_mfma_f32_16x16x32_f16(ah1, bl1, acc1[nt], 0, 0, 0);
                acc1[nt] = __builtin_amdgcn_mfma_f32_16x16x32_f16(aflo[0], bh0, acc1[nt], 0, 0, 0);
                acc1[nt] = __builtin_amdgcn_mfma_f32_16x16x32_f16(aflo[1], bh1, acc1[nt], 0, 0, 0);
            }
        }

        float rs[4];
        #pragma unroll
        for (int t = 0; t < 4; ++t) {
            const int ig = r0 + kg * 4 + t;
            float s = 0.f;
            #pragma unroll
            for (int nt = 0; nt < 8; ++nt) {
                int jg = nt * 16 + ml;
                s += (jg <= ig) ? acc1[nt][t] : 0.f;
            }
            const int f0 = ml * 4;
            half4 ql = *(const half4*)(qlog + base + (size_t)ig * D_MODEL + f0);
            #pragma unroll
            for (int u = 0; u < 4; ++u)
                s += ((float)sq[ig * 72 + f0 + u] + (float)ql[u]) * szz[f0 + u];
            s += __shfl_xor(s, 1, 64);
            s += __shfl_xor(s, 2, 64);
            s += __shfl_xor(s, 4, 64);
            s += __shfl_xor(s, 8, 64);
            rs[t] = s;
        }

        #pragma unroll
        for (int nt = 0; nt < 8; ++nt) {
            #pragma unroll
            for (int t = 0; t < 4; ++t) {
                int lr = w * 16 + kg * 4 + t;
                int ig = h2 * 64 + lr;
                int jg = nt * 16 + ml;
                float val = (jg <= ig) ? acc1[nt][t] : 0.f;
                ssc[lr * 136 + jg] = (_Float16)val;
            }
        }
        __syncthreads();

        f32x4 acc2[4];
        #pragma unroll
        for (int et = 0; et < 4; ++et) { f32x4 z = {0.f,0.f,0.f,0.f}; acc2[et] = z; }
        const int nkit = (h2 == 0) ? 2 : 4;
        #pragma unroll
        for (int et = 0; et < 4; ++et) {
            for (int kit = 0; kit < nkit; ++kit) {
                half8 af = *(const half8*)&ssc[(w * 16 + ml) * 136 + kit * 32 + kg * 8];
                half8 bf = *(const half8*)&sv[(et * 16 + ml) * 136 + kit * 32 + kg * 8];
                acc2[et] = __builtin_amdgcn_mfma_f32_16x16x32_f16(af, bf, acc2[et], 0, 0, 0);
            }
            #pragma unroll
            for (int kit = 0; kit < 2; ++kit) {
                half8 af = *(const half8*)&sq[(r0 + ml) * 72 + kit * 32 + kg * 8];
                half8 bf = *(const half8*)&sS[(et * 16 + ml) * 72 + kit * 32 + kg * 8];
                acc2[et] = __builtin_amdgcn_mfma_f32_16x16x32_f16(af, bf, acc2[et], 0, 0, 0);
            }
        }
        #pragma unroll
        for (int t = 0; t < 4; ++t) {
            int lr = w * 16 + kg * 4 + t;
            int ig = h2 * 64 + lr;
            float rc = 0.015625f / fmaxf(rs[t], EPS_DEN);
            #pragma unroll
            for (int et = 0; et < 4; ++et) {
                int e = et * 16 + ml;
                O16[base + (size_t)ig * D_MODEL + e] = (_Float16)(acc2[et][t] * rc);
            }
        }
        __syncthreads();
    }
}

// ---------------------------------------------------------------------------
extern "C" void kernel_launch(void* const* d_in, const int* in_sizes, int n_in,
                              void* d_out, int out_size, void* d_ws, size_t ws_size,
                              hipStream_t stream) {
    const float* x  = (const float*)d_in[0];
    const float* Wq = (const float*)d_in[1];
    const float* bq = (const float*)d_in[2];
    const float* Wk = (const float*)d_in[3];
    const float* bk = (const float*)d_in[4];
    const float* Wv = (const float*)d_in[5];
    const float* bv = (const float*)d_in[6];
    const float* Wo = (const float*)d_in[7];
    const float* bo = (const float*)d_in[8];
    float* out = (float*)d_out;

    char* p = (char*)d_ws;
    _Float16* x2   = (_Float16*)p;  p += (size_t)NTOK * 2048 * 2;
    _Float16* w2q  = (_Float16*)p;  p += (size_t)1024 * 2048 * 2;
    _Float16* w2k  = (_Float16*)p;  p += (size_t)1024 * 2048 * 2;   // contiguous after w2q
    _Float16* wv16 = (_Float16*)p;  p += (size_t)1024 * 1024 * 2;
    _Float16* wo16 = (_Float16*)p;  p += (size_t)1024 * 1024 * 2;
    _Float16* qlo  = (_Float16*)p;  p += (size_t)NTOK * 1024 * 2;
    _Float16* klo  = (_Float16*)p;  p += (size_t)NTOK * 1024 * 2;
    _Float16* q16  = (_Float16*)p;  p += (size_t)NTOK * 1024 * 2;
    _Float16* k16  = (_Float16*)p;  p += (size_t)NTOK * 1024 * 2;
    _Float16* v16  = (_Float16*)p;  p += (size_t)NTOK * 1024 * 2;
    float* kvT  = (float*)p;        p += (size_t)1024 * 4096 * 4;
    float* ksb  = (float*)p;        p += (size_t)1024 * 64 * 4;
    float* bqk  = (float*)p;        p += 2048 * 4;
    _Float16* attn16 = x2;  // x2 dead after gemm_qkv

    prep<<<6152, 256, 0, stream>>>(x, Wq, Wk, Wv, Wo, bq, bk,
                                   x2, w2q, w2k, wv16, wo16, bqk);

    gemm_qkv<<<dim3(64, 24), 256, 0, stream>>>(x2, w2q, wv16, bqk, bv,
                                               qlo, klo, q16, k16, v16, ksb);

    chunk_stats<<<1024, 256, 0, stream>>>(k16, v16, kvT);
    scan_chunks<<<1024, 256, 0, stream>>>(kvT, ksb);
    attn_core<<<1024, 256, 0, stream>>>(q16, k16, v16, qlo, klo, kvT, ksb, attn16);

    gemm_out<<<dim3(64, 8), 256, 0, stream>>>(attn16, wo16, bo, out);
}

// Round 6
// 330.614 us; speedup vs baseline: 1.0761x; 1.0241x over previous
//
#include <hip/hip_runtime.h>
#include <math.h>

#define D_MODEL 1024
#define HEADS   16
#define HDIM    64
#define CHUNK   128
#define B_SZ    4
#define L_SEQ   2048
#define NCHUNK  16
#define NTOK    8192
#define EPS_DEN 1e-3f

typedef _Float16 half8 __attribute__((ext_vector_type(8)));
typedef _Float16 half4 __attribute__((ext_vector_type(4)));
typedef float    f32x4 __attribute__((ext_vector_type(4)));

__device__ __forceinline__ void gld_lds16(const void* g, void* l) {
    __builtin_amdgcn_global_load_lds(
        (const __attribute__((address_space(1))) void*)g,
        (__attribute__((address_space(3))) void*)l, 16, 0, 0);
}

// ---------------------------------------------------------------------------
// Fused preprocessing: x->hi|lo, Wq->hi|lo, Wk->hi|lo, Wv->f16, Wo->f16,
// bias concat [bq|bk].
// ---------------------------------------------------------------------------
__global__ __launch_bounds__(256) void prep(
    const float* __restrict__ x,  const float* __restrict__ Wq,
    const float* __restrict__ Wk, const float* __restrict__ Wv,
    const float* __restrict__ Wo, const float* __restrict__ bq,
    const float* __restrict__ bk,
    _Float16* __restrict__ x2,  _Float16* __restrict__ w2q,
    _Float16* __restrict__ w2k, _Float16* __restrict__ wv16,
    _Float16* __restrict__ wo16, float* __restrict__ bqk) {
    const int bid = blockIdx.x;
    if (bid < 5120) {           // split jobs: x / Wq / Wk
        const float* src; _Float16* dst; int t;
        if (bid < 4096)      { src = x;  dst = x2;  t = bid * 256 + threadIdx.x; }
        else if (bid < 4608) { src = Wq; dst = w2q; t = (bid - 4096) * 256 + threadIdx.x; }
        else                 { src = Wk; dst = w2k; t = (bid - 4608) * 256 + threadIdx.x; }
        int m = t >> 7, kc = (t & 127) << 3;
        const float* s = src + (size_t)m * 1024 + kc;
        f32x4 a = *(const f32x4*)s;
        f32x4 b = *(const f32x4*)(s + 4);
        float xs[8] = {a.x, a.y, a.z, a.w, b.x, b.y, b.z, b.w};
        half8 hi, lo;
        #pragma unroll
        for (int u = 0; u < 8; ++u) {
            _Float16 h = (_Float16)xs[u];
            hi[u] = h;
            lo[u] = (_Float16)(xs[u] - (float)h);
        }
        *(half8*)(dst + (size_t)m * 2048 + kc)        = hi;
        *(half8*)(dst + (size_t)m * 2048 + 1024 + kc) = lo;
    } else if (bid < 6144) {    // conv jobs: Wv / Wo
        const float* src; _Float16* dst; int t;
        if (bid < 5632) { src = Wv; dst = wv16; t = (bid - 5120) * 256 + threadIdx.x; }
        else            { src = Wo; dst = wo16; t = (bid - 5632) * 256 + threadIdx.x; }
        int m = t >> 7, kc = (t & 127) << 3;
        const float* s = src + (size_t)m * 1024 + kc;
        f32x4 a = *(const f32x4*)s;
        f32x4 b = *(const f32x4*)(s + 4);
        float xs[8] = {a.x, a.y, a.z, a.w, b.x, b.y, b.z, b.w};
        half8 hv;
        #pragma unroll
        for (int u = 0; u < 8; ++u) hv[u] = (_Float16)xs[u];
        *(half8*)(dst + (size_t)m * 1024 + kc) = hv;
    } else {
        int i = (bid - 6144) * 256 + threadIdx.x;
        bqk[i] = (i < 1024) ? bq[i] : bk[i - 1024];
    }
}

// ---------------------------------------------------------------------------
// Fused q/k/v projection GEMM (unchanged from R5 — session plateau ~164 us).
// ---------------------------------------------------------------------------
__global__ __launch_bounds__(256, 4) void gemm_qkv(
    const _Float16* __restrict__ A,    // x2, lda 2048
    const _Float16* __restrict__ Bqk,  // [w2q;w2k], ldb 2048
    const _Float16* __restrict__ Bv,   // wv16, ldb 1024
    const float* __restrict__ bqk, const float* __restrict__ bv,
    _Float16* __restrict__ Qlo, _Float16* __restrict__ Klo,
    _Float16* __restrict__ Q16, _Float16* __restrict__ K16,
    _Float16* __restrict__ V16, float* __restrict__ ksum) {
    // two buffers of [A 128x32 | B 128x32] = 16KB each; slab reuses sbuf.
    __shared__ __align__(16) _Float16 sbuf[2 * 8192];
    __shared__ float sksum[2][128];
    _Float16* sC16 = sbuf;              // epilogue slab (needs 4352h <= 8192h)

    const int cb   = blockIdx.y;
    const int isqk = (cb < 16);
    const int isk  = (cb >= 8 && cb < 16);
    const int tid  = threadIdx.x;
    const int lane = tid & 63;
    const int w    = tid >> 6;
    const int row0 = blockIdx.x * 128;
    const int col0 = cb * 128;               // 0..3071 global col space
    const int wm   = (w & 1) * 64;
    const int wn   = (w >> 1) * 64;

    const _Float16* B = isqk ? Bqk : Bv;
    const int ldb     = isqk ? 2048 : 1024;
    const int bcol0   = isqk ? col0 : col0 - 2048;
    const int kits    = isqk ? 96 : 32;

    const int ch0 = w * 64 + lane;
    const int rS0 = ch0 >> 2;
    const int cS0 = (ch0 & 3) ^ ((rS0 >> 1) & 3);
    const int ch1 = ch0 + 256;
    const int rS1 = ch1 >> 2;
    const int cS1 = (ch1 & 3) ^ ((rS1 >> 1) & 3);

    const _Float16* gA0 = A + (size_t)(row0  + rS0) * 2048 + cS0 * 8;
    const _Float16* gA1 = A + (size_t)(row0  + rS1) * 2048 + cS1 * 8;
    const _Float16* gB0 = B + (size_t)(bcol0 + rS0) * ldb  + cS0 * 8;
    const _Float16* gB1 = B + (size_t)(bcol0 + rS1) * ldb  + cS1 * 8;

    auto stage = [&](int kt, int bsel) {
        const int k0   = kt * 32;
        const int acol = (k0 < 2048) ? k0 : k0 - 2048;
        const int bcol = (k0 < 1024) ? k0 : k0 - 1024;
        _Float16* l = sbuf + bsel * 8192;
        gld_lds16(gA0 + acol, l + w * 512);
        gld_lds16(gA1 + acol, l + 2048 + w * 512);
        gld_lds16(gB0 + bcol, l + 4096 + w * 512);
        gld_lds16(gB1 + bcol, l + 6144 + w * 512);
    };

    f32x4 acc[4][4];
    #pragma unroll
    for (int i = 0; i < 4; ++i)
        #pragma unroll
        for (int j = 0; j < 4; ++j) { f32x4 z = {0.f, 0.f, 0.f, 0.f}; acc[i][j] = z; }

    const int ml = lane & 15;
    const int kg = lane >> 4;
    int offA[4], offB[4];
    #pragma unroll
    for (int i = 0; i < 4; ++i) {
        int r  = wm + i * 16 + ml;
        offA[i] = r * 32 + (kg ^ ((r >> 1) & 3)) * 8;
        int rn = wn + i * 16 + ml;
        offB[i] = 4096 + rn * 32 + (kg ^ ((rn >> 1) & 3)) * 8;
    }

    stage(0, 0);
    asm volatile("s_waitcnt vmcnt(0)\n\ts_barrier" ::: "memory");
    int cur = 0;
    for (int t = 0; t < kits; ++t) {
        if (t + 1 < kits) stage(t + 1, cur ^ 1);   // issue BEFORE compute
        const _Float16* lb = sbuf + cur * 8192;
        half8 af[4], bf[4];
        #pragma unroll
        for (int i = 0; i < 4; ++i) {
            af[i] = *(const half8*)&lb[offA[i]];
            bf[i] = *(const half8*)&lb[offB[i]];
        }
        __builtin_amdgcn_s_setprio(1);
        #pragma unroll
        for (int i = 0; i < 4; ++i)
            #pragma unroll
            for (int j = 0; j < 4; ++j)
                acc[i][j] = __builtin_amdgcn_mfma_f32_16x16x32_f16(af[i], bf[j], acc[i][j], 0, 0, 0);
        __builtin_amdgcn_s_setprio(0);
        asm volatile("s_waitcnt vmcnt(0)\n\ts_barrier" ::: "memory");
        cur ^= 1;
    }

    // output routing
    const int colq = isqk ? ((col0 < 1024) ? col0 : col0 - 1024) : (col0 - 2048);
    _Float16* Ylo  = (col0 < 1024) ? Qlo : Klo;      // only used when isqk
    _Float16* Y16  = isqk ? ((col0 < 1024) ? Q16 : K16) : V16;

    const int rg = lane >> 4;
    #pragma unroll
    for (int j = 0; j < 4; ++j) {
        const float bvb = isqk ? bqk[col0 + wn + j * 16 + ml]
                               : bv[colq + wn + j * 16 + ml];
        const int nn = colq + wn + j * 16 + ml;
        #pragma unroll
        for (int i = 0; i < 4; ++i) {
            #pragma unroll
            for (int t = 0; t < 4; ++t) {
                float vv = acc[i][j][t] + bvb;
                if (isqk) {
                    vv = vv / (1.f + expf(-vv));     // silu
                    int mm = row0 + wm + i * 16 + rg * 4 + t;
                    _Float16 hv = (_Float16)vv;      // hi (same cast as slab)
                    Ylo[(size_t)mm * 1024 + nn] = (_Float16)(vv - (float)hv);
                }
                acc[i][j][t] = vv;
            }
        }
    }

    // fused ksum for k-blocks: this tile = chunk (b,n) x 2 heads.
    if (isk) {
        #pragma unroll
        for (int j = 0; j < 4; ++j) {
            float ps = 0.f;
            #pragma unroll
            for (int i = 0; i < 4; ++i)
                #pragma unroll
                for (int t = 0; t < 4; ++t) ps += acc[i][j][t];
            // reduce over the 4 rg lane groups (lanes kg*16+ml)
            ps += __shfl_xor(ps, 16, 64);
            ps += __shfl_xor(ps, 32, 64);
            if (kg == 0) sksum[wm >> 6][wn + j * 16 + ml] = ps;
        }
        __syncthreads();
        if (tid < 128) {
            const int b = row0 >> 11;
            const int n = (row0 >> 7) & 15;
            const int cg = colq + tid;         // global k-col
            const int h = cg >> 6, f = cg & 63;
            ksum[(size_t)(((b * 16 + h) * 16 + n)) * 64 + f] =
                sksum[0][tid] + sksum[1][tid];
        }
        __syncthreads();
    }

    // f16 via LDS slab transpose (4 slabs of 32 rows), slab buffer = sbuf
    for (int s = 0; s < 4; ++s) {
        if ((wm == 0) == (s < 2)) {
            const int ib = (s & 1) * 2;
            #pragma unroll
            for (int ii = 0; ii < 2; ++ii)
                #pragma unroll
                for (int j = 0; j < 4; ++j)
                    #pragma unroll
                    for (int t = 0; t < 4; ++t) {
                        int lr = ii * 16 + rg * 4 + t;
                        sC16[lr * 136 + wn + j * 16 + ml] = (_Float16)acc[ib + ii][j][t];
                    }
        }
        __syncthreads();
        #pragma unroll
        for (int u = 0; u < 2; ++u) {
            int c = u * 256 + tid;
            int r = c >> 4, cc = (c & 15) * 8;
            half8 hv = *(const half8*)&sC16[r * 136 + cc];
            *(half8*)(Y16 + (size_t)(row0 + 32 * s + r) * 1024 + colq + cc) = hv;
        }
        __syncthreads();
    }
}

// ---------------------------------------------------------------------------
// Final output GEMM: out = attn16 * wo16^T * 64 + bo. Tile 128x128, BK=32,
// 2-phase double buffer (unchanged from R5). grid dim3(64, 8).
// ---------------------------------------------------------------------------
__global__ __launch_bounds__(256, 4) void gemm_out(
    const _Float16* __restrict__ A,   // attn16, lda 1024
    const _Float16* __restrict__ B,   // wo16, ldb 1024
    const float* __restrict__ bias,
    float* __restrict__ Y) {
    __shared__ __align__(16) _Float16 sbuf[2 * 8192];  // [A 128x32 | B 128x32] x2

    const int tid  = threadIdx.x;
    const int lane = tid & 63;
    const int w    = tid >> 6;
    const int row0 = blockIdx.x * 128;
    const int col0 = blockIdx.y * 128;
    const int wm   = (w & 1) * 64;
    const int wn   = (w >> 1) * 64;

    const int ch0 = w * 64 + lane;
    const int rS0 = ch0 >> 2;
    const int cS0 = (ch0 & 3) ^ ((rS0 >> 1) & 3);
    const int ch1 = ch0 + 256;
    const int rS1 = ch1 >> 2;
    const int cS1 = (ch1 & 3) ^ ((rS1 >> 1) & 3);

    const _Float16* gA0 = A + (size_t)(row0 + rS0) * 1024 + cS0 * 8;
    const _Float16* gA1 = A + (size_t)(row0 + rS1) * 1024 + cS1 * 8;
    const _Float16* gB0 = B + (size_t)(col0 + rS0) * 1024 + cS0 * 8;
    const _Float16* gB1 = B + (size_t)(col0 + rS1) * 1024 + cS1 * 8;

    auto stage = [&](int kt, int bsel) {
        const int k0 = kt * 32;
        _Float16* l = sbuf + bsel * 8192;
        gld_lds16(gA0 + k0, l + w * 512);
        gld_lds16(gA1 + k0, l + 2048 + w * 512);
        gld_lds16(gB0 + k0, l + 4096 + w * 512);
        gld_lds16(gB1 + k0, l + 6144 + w * 512);
    };

    f32x4 acc[4][4];
    #pragma unroll
    for (int i = 0; i < 4; ++i)
        #pragma unroll
        for (int j = 0; j < 4; ++j) { f32x4 z = {0.f, 0.f, 0.f, 0.f}; acc[i][j] = z; }

    const int ml = lane & 15;
    const int kg = lane >> 4;
    int offA[4], offB[4];
    #pragma unroll
    for (int i = 0; i < 4; ++i) {
        int r  = wm + i * 16 + ml;
        offA[i] = r * 32 + (kg ^ ((r >> 1) & 3)) * 8;
        int rn = wn + i * 16 + ml;
        offB[i] = 4096 + rn * 32 + (kg ^ ((rn >> 1) & 3)) * 8;
    }

    stage(0, 0);
    asm volatile("s_waitcnt vmcnt(0)\n\ts_barrier" ::: "memory");
    int cur = 0;
    for (int kit = 0; kit < 32; ++kit) {
        if (kit + 1 < 32) stage(kit + 1, cur ^ 1);
        const _Float16* lb = sbuf + cur * 8192;
        half8 af[4], bf[4];
        #pragma unroll
        for (int i = 0; i < 4; ++i) {
            af[i] = *(const half8*)&lb[offA[i]];
            bf[i] = *(const half8*)&lb[offB[i]];
        }
        __builtin_amdgcn_s_setprio(1);
        #pragma unroll
        for (int i = 0; i < 4; ++i)
            #pragma unroll
            for (int j = 0; j < 4; ++j)
                acc[i][j] = __builtin_amdgcn_mfma_f32_16x16x32_f16(af[i], bf[j], acc[i][j], 0, 0, 0);
        __builtin_amdgcn_s_setprio(0);
        asm volatile("s_waitcnt vmcnt(0)\n\ts_barrier" ::: "memory");
        cur ^= 1;
    }

    const int rg = lane >> 4;
    #pragma unroll
    for (int j = 0; j < 4; ++j) {
        const int nn = col0 + wn + j * 16 + ml;
        const float bvb = bias[nn];
        #pragma unroll
        for (int i = 0; i < 4; ++i) {
            #pragma unroll
            for (int t = 0; t < 4; ++t) {
                int mm = row0 + wm + i * 16 + rg * 4 + t;
                Y[(size_t)mm * 1024 + nn] = acc[i][j][t] * 64.f + bvb;
            }
        }
    }
}

// ---------------------------------------------------------------------------
// chunk stats: kvT[blk][e][f] = sum_j v16[j][e]*k16[j][f] via MFMA.
// ---------------------------------------------------------------------------
__global__ __launch_bounds__(256) void chunk_stats(
    const _Float16* __restrict__ k16g, const _Float16* __restrict__ v16g,
    float* __restrict__ kvT) {
    const int blk = blockIdx.x;
    const int n = blk & 15, bh = blk >> 4, h = bh & 15, b = bh >> 4;
    const size_t base = ((size_t)b * L_SEQ + (size_t)n * CHUNK) * D_MODEL + (size_t)h * HDIM;

    __shared__ __align__(16) _Float16 sv[64 * 136];
    __shared__ __align__(16) _Float16 sk[64 * 136];

    const int tid = threadIdx.x;
    #pragma unroll
    for (int p = 0; p < 4; ++p) {
        int idx = p * 256 + tid;
        int j = idx >> 3, c = idx & 7;
        half8 vv = *(const half8*)(v16g + base + (size_t)j * D_MODEL + c * 8);
        half8 kk = *(const half8*)(k16g + base + (size_t)j * D_MODEL + c * 8);
        #pragma unroll
        for (int u = 0; u < 8; ++u) {
            sv[(c * 8 + u) * 136 + j] = vv[u];
            sk[(c * 8 + u) * 136 + j] = kk[u];
        }
    }
    __syncthreads();

    const int lane = tid & 63;
    const int w    = tid >> 6;
    const int ml   = lane & 15;
    const int kg   = lane >> 4;

    f32x4 acc[4];
    #pragma unroll
    for (int ft = 0; ft < 4; ++ft) { f32x4 z = {0.f,0.f,0.f,0.f}; acc[ft] = z; }
    #pragma unroll
    for (int ft = 0; ft < 4; ++ft)
        #pragma unroll
        for (int kit = 0; kit < 4; ++kit) {
            half8 af = *(const half8*)&sv[(w * 16 + ml) * 136 + kit * 32 + kg * 8];
            half8 bf = *(const half8*)&sk[(ft * 16 + ml) * 136 + kit * 32 + kg * 8];
            acc[ft] = __builtin_amdgcn_mfma_f32_16x16x32_f16(af, bf, acc[ft], 0, 0, 0);
        }
    float* o = kvT + (size_t)blk * 4096;
    #pragma unroll
    for (int ft = 0; ft < 4; ++ft)
        #pragma unroll
        for (int t = 0; t < 4; ++t) {
            int e = w * 16 + kg * 4 + t;
            o[e * 64 + ft * 16 + ml] = acc[ft][t];
        }
}

// ---------------------------------------------------------------------------
// Exclusive cumsum over chunk axis. Reads fp32 kvT, emits the prefix directly
// as f16 (attn converts to f16 anyway — identical values, half the traffic,
// and kvT is no longer rewritten). ksum scan stays fp32.
// ---------------------------------------------------------------------------
__global__ __launch_bounds__(256) void scan_chunks(const float* __restrict__ kvT,
                                                   _Float16* __restrict__ kv16,
                                                   float* __restrict__ ksum) {
    const int bh  = blockIdx.x >> 4;
    const int seg = blockIdx.x & 15;
    const int idx = seg * 256 + threadIdx.x;
    const float* base = kvT + (size_t)bh * NCHUNK * 4096 + idx;
    _Float16*   obase = kv16 + (size_t)bh * NCHUNK * 4096 + idx;
    float run = 0.f;
    #pragma unroll
    for (int nn = 0; nn < NCHUNK; ++nn) {
        float t = base[(size_t)nn * 4096];
        obase[(size_t)nn * 4096] = (_Float16)run;
        run += t;
    }
    if (seg == 0 && threadIdx.x < 64) {
        float* zb = ksum + (size_t)bh * NCHUNK * 64 + threadIdx.x;
        float r2 = 0.f;
        #pragma unroll
        for (int nn = 0; nn < NCHUNK; ++nn) {
            float t = zb[nn * 64];
            zb[nn * 64] = r2;
            r2 += t;
        }
    }
}

// ---------------------------------------------------------------------------
// MFMA attention core with fused fp32-grade denominator.
// R6 changes (math bit-identical to R5):
//  - klo tile (128x64) staged into LDS (reusing ssc, chunk-XOR layout) so the
//    QK^T lo-passes read coalesced LDS instead of 2KB-strided global gathers.
//    Both h2-halves' acc1 are computed before ssc is overwritten.
//  - S-state read as f16 directly (kv16) — no fp32 load + convert.
// ---------------------------------------------------------------------------
__global__ __launch_bounds__(256) void attn_core(
    const _Float16* __restrict__ q16g, const _Float16* __restrict__ k16g,
    const _Float16* __restrict__ v16g, const _Float16* __restrict__ qlog,
    const _Float16* __restrict__ klog, const _Float16* __restrict__ ST16,
    const float* __restrict__ zg, _Float16* __restrict__ O16) {
    const int blk = blockIdx.x;
    const int n = blk & 15, bh = blk >> 4, h = bh & 15, b = bh >> 4;
    const size_t base = ((size_t)b * L_SEQ + (size_t)n * CHUNK) * D_MODEL + (size_t)h * HDIM;

    __shared__ __align__(16) _Float16 sq [128 * 72];
    __shared__ __align__(16) _Float16 sk [128 * 72];
    __shared__ __align__(16) _Float16 sv [64 * 136];
    __shared__ __align__(16) _Float16 sS [64 * 72];
    __shared__ __align__(16) _Float16 ssc[64 * 136];   // 8704h; doubles as klo stage
    __shared__ float szz[64];
    _Float16* sklo = ssc;   // klo[j][chunk c] at j*64 + ((c^(j&7))<<3); 8192h

    const int tid = threadIdx.x;
    #pragma unroll
    for (int p = 0; p < 4; ++p) {
        int idx = p * 256 + tid;
        int j = idx >> 3, c = idx & 7;
        *(half8*)&sq[j * 72 + c * 8] = *(const half8*)(q16g + base + (size_t)j * D_MODEL + c * 8);
        *(half8*)&sk[j * 72 + c * 8] = *(const half8*)(k16g + base + (size_t)j * D_MODEL + c * 8);
        half8 vv = *(const half8*)(v16g + base + (size_t)j * D_MODEL + c * 8);
        #pragma unroll
        for (int u = 0; u < 8; ++u) sv[(c * 8 + u) * 136 + j] = vv[u];
        half8 kl = *(const half8*)(klog + base + (size_t)j * D_MODEL + c * 8);
        *(half8*)&sklo[j * 64 + ((c ^ (j & 7)) << 3)] = kl;
    }
    #pragma unroll
    for (int p = 0; p < 2; ++p) {
        int idx = p * 256 + tid;
        int e = idx >> 3, c = idx & 7;
        *(half8*)&sS[e * 72 + c * 8] =
            *(const half8*)(ST16 + (size_t)blk * 4096 + e * 64 + c * 8);
    }
    if (tid < 64) szz[tid] = zg[(size_t)blk * 64 + tid];
    __syncthreads();

    const int lane = tid & 63;
    const int w    = tid >> 6;
    const int ml   = lane & 15;
    const int kg   = lane >> 4;

    // ---- QK^T (hi*hi + hi*lo + lo*hi) for BOTH row-halves, klo from LDS ----
    f32x4 acc1a[8], acc1b[8];
    #pragma unroll
    for (int nt = 0; nt < 8; ++nt) {
        f32x4 z = {0.f,0.f,0.f,0.f}; acc1a[nt] = z; acc1b[nt] = z;
    }

    auto qk_acc = [&](f32x4 (&a1)[8], int r0) {
        const int rowmax = r0 + 15;
        half8 aflo0 = *(const half8*)(qlog + base + (size_t)(r0 + ml) * D_MODEL + kg * 8);
        half8 aflo1 = *(const half8*)(qlog + base + (size_t)(r0 + ml) * D_MODEL + 32 + kg * 8);
        #pragma unroll
        for (int nt = 0; nt < 8; ++nt) {
            if (nt * 16 <= rowmax) {
                #pragma unroll
                for (int kit = 0; kit < 2; ++kit) {
                    half8 af = *(const half8*)&sq[(r0 + ml) * 72 + kit * 32 + kg * 8];
                    half8 bf = *(const half8*)&sk[(nt * 16 + ml) * 72 + kit * 32 + kg * 8];
                    a1[nt] = __builtin_amdgcn_mfma_f32_16x16x32_f16(af, bf, a1[nt], 0, 0, 0);
                }
            }
        }
        #pragma unroll
        for (int nt = 0; nt < 8; ++nt) {
            if (nt * 16 <= rowmax) {
                const int jr = nt * 16 + ml;
                half8 bl0 = *(const half8*)&sklo[jr * 64 + ((kg ^ (jr & 7)) << 3)];
                half8 bl1 = *(const half8*)&sklo[jr * 64 + (((4 + kg) ^ (jr & 7)) << 3)];
                half8 ah0 = *(const half8*)&sq[(r0 + ml) * 72 + kg * 8];
                half8 ah1 = *(const half8*)&sq[(r0 + ml) * 72 + 32 + kg * 8];
                half8 bh0 = *(const half8*)&sk[jr * 72 + kg * 8];
                half8 bh1 = *(const half8*)&sk[jr * 72 + 32 + kg * 8];
                a1[nt] = __builtin_amdgcn_mfma_f32_16x16x32_f16(ah0, bl0, a1[nt], 0, 0, 0);
                a1[nt] = __builtin_amdgcn_mfma_f32_16x16x32_f16(ah1, bl1, a1[nt], 0, 0, 0);
                a1[nt] = __builtin_amdgcn_mfma_f32_16x16x32_f16(aflo0, bh0, a1[nt], 0, 0, 0);
                a1[nt] = __builtin_amdgcn_mfma_f32_16x16x32_f16(aflo1, bh1, a1[nt], 0, 0, 0);
            }
        }
    };
    qk_acc(acc1a, w * 16);
    qk_acc(acc1b, 64 + w * 16);
    __syncthreads();   // all waves done reading sklo (=ssc) before S overwrite

    // ---- per-half: den, masked-S to LDS, PV + qS, store ----
    auto finish = [&](f32x4 (&a1)[8], int h2, int nkit) {
        const int r0 = h2 * 64 + w * 16;
        float rs[4];
        #pragma unroll
        for (int t = 0; t < 4; ++t) {
            const int ig = r0 + kg * 4 + t;
            float s = 0.f;
            #pragma unroll
            for (int nt = 0; nt < 8; ++nt) {
                int jg = nt * 16 + ml;
                s += (jg <= ig) ? a1[nt][t] : 0.f;
            }
            const int f0 = ml * 4;
            half4 ql = *(const half4*)(qlog + base + (size_t)ig * D_MODEL + f0);
            #pragma unroll
            for (int u = 0; u < 4; ++u)
                s += ((float)sq[ig * 72 + f0 + u] + (float)ql[u]) * szz[f0 + u];
            s += __shfl_xor(s, 1, 64);
            s += __shfl_xor(s, 2, 64);
            s += __shfl_xor(s, 4, 64);
            s += __shfl_xor(s, 8, 64);
            rs[t] = s;
        }

        #pragma unroll
        for (int nt = 0; nt < 8; ++nt) {
            #pragma unroll
            for (int t = 0; t < 4; ++t) {
                int lr = w * 16 + kg * 4 + t;
                int ig = h2 * 64 + lr;
                int jg = nt * 16 + ml;
                float val = (jg <= ig) ? a1[nt][t] : 0.f;
                ssc[lr * 136 + jg] = (_Float16)val;
            }
        }
        __syncthreads();

        f32x4 acc2[4];
        #pragma unroll
        for (int et = 0; et < 4; ++et) { f32x4 z = {0.f,0.f,0.f,0.f}; acc2[et] = z; }
        #pragma unroll
        for (int et = 0; et < 4; ++et) {
            for (int kit = 0; kit < nkit; ++kit) {
                half8 af = *(const half8*)&ssc[(w * 16 + ml) * 136 + kit * 32 + kg * 8];
                half8 bf = *(const half8*)&sv[(et * 16 + ml) * 136 + kit * 32 + kg * 8];
                acc2[et] = __builtin_amdgcn_mfma_f32_16x16x32_f16(af, bf, acc2[et], 0, 0, 0);
            }
            #pragma unroll
            for (int kit = 0; kit < 2; ++kit) {
                half8 af = *(const half8*)&sq[(r0 + ml) * 72 + kit * 32 + kg * 8];
                half8 bf = *(const half8*)&sS[(et * 16 + ml) * 72 + kit * 32 + kg * 8];
                acc2[et] = __builtin_amdgcn_mfma_f32_16x16x32_f16(af, bf, acc2[et], 0, 0, 0);
            }
        }
        #pragma unroll
        for (int t = 0; t < 4; ++t) {
            int lr = w * 16 + kg * 4 + t;
            int ig = h2 * 64 + lr;
            float rc = 0.015625f / fmaxf(rs[t], EPS_DEN);
            #pragma unroll
            for (int et = 0; et < 4; ++et) {
                int e = et * 16 + ml;
                O16[base + (size_t)ig * D_MODEL + e] = (_Float16)(acc2[et][t] * rc);
            }
        }
        __syncthreads();
    };
    finish(acc1a, 0, 2);
    finish(acc1b, 1, 4);
}

// ---------------------------------------------------------------------------
extern "C" void kernel_launch(void* const* d_in, const int* in_sizes, int n_in,
                              void* d_out, int out_size, void* d_ws, size_t ws_size,
                              hipStream_t stream) {
    const float* x  = (const float*)d_in[0];
    const float* Wq = (const float*)d_in[1];
    const float* bq = (const float*)d_in[2];
    const float* Wk = (const float*)d_in[3];
    const float* bk = (const float*)d_in[4];
    const float* Wv = (const float*)d_in[5];
    const float* bv = (const float*)d_in[6];
    const float* Wo = (const float*)d_in[7];
    const float* bo = (const float*)d_in[8];
    float* out = (float*)d_out;

    char* p = (char*)d_ws;
    _Float16* x2   = (_Float16*)p;  p += (size_t)NTOK * 2048 * 2;
    _Float16* w2q  = (_Float16*)p;  p += (size_t)1024 * 2048 * 2;
    _Float16* w2k  = (_Float16*)p;  p += (size_t)1024 * 2048 * 2;   // contiguous after w2q
    _Float16* wv16 = (_Float16*)p;  p += (size_t)1024 * 1024 * 2;
    _Float16* wo16 = (_Float16*)p;  p += (size_t)1024 * 1024 * 2;
    _Float16* qlo  = (_Float16*)p;  p += (size_t)NTOK * 1024 * 2;
    _Float16* klo  = (_Float16*)p;  p += (size_t)NTOK * 1024 * 2;
    _Float16* q16  = (_Float16*)p;  p += (size_t)NTOK * 1024 * 2;
    _Float16* k16  = (_Float16*)p;  p += (size_t)NTOK * 1024 * 2;
    _Float16* v16  = (_Float16*)p;  p += (size_t)NTOK * 1024 * 2;
    float* kvT  = (float*)p;        p += (size_t)1024 * 4096 * 4;
    _Float16* kv16 = (_Float16*)p;  p += (size_t)1024 * 4096 * 2;
    float* ksb  = (float*)p;        p += (size_t)1024 * 64 * 4;
    float* bqk  = (float*)p;        p += 2048 * 4;
    _Float16* attn16 = x2;  // x2 dead after gemm_qkv

    prep<<<6152, 256, 0, stream>>>(x, Wq, Wk, Wv, Wo, bq, bk,
                                   x2, w2q, w2k, wv16, wo16, bqk);

    gemm_qkv<<<dim3(64, 24), 256, 0, stream>>>(x2, w2q, wv16, bqk, bv,
                                               qlo, klo, q16, k16, v16, ksb);

    chunk_stats<<<1024, 256, 0, stream>>>(k16, v16, kvT);
    scan_chunks<<<1024, 256, 0, stream>>>(kvT, kv16, ksb);
    attn_core<<<1024, 256, 0, stream>>>(q16, k16, v16, qlo, klo, kv16, ksb, attn16);

    gemm_out<<<dim3(64, 8), 256, 0, stream>>>(attn16, wo16, bo, out);
}

// Round 7
// 295.521 us; speedup vs baseline: 1.2039x; 1.1188x over previous
//
#include <hip/hip_runtime.h>
#include <math.h>

#define D_MODEL 1024
#define HEADS   16
#define HDIM    64
#define CHUNK   128
#define B_SZ    4
#define L_SEQ   2048
#define NCHUNK  16
#define NTOK    8192
#define EPS_DEN 1e-3f

typedef _Float16 half8 __attribute__((ext_vector_type(8)));
typedef _Float16 half4 __attribute__((ext_vector_type(4)));
typedef float    f32x4 __attribute__((ext_vector_type(4)));

__device__ __forceinline__ void gld_lds16(const void* g, void* l) {
    __builtin_amdgcn_global_load_lds(
        (const __attribute__((address_space(1))) void*)g,
        (__attribute__((address_space(3))) void*)l, 16, 0, 0);
}

// ---------------------------------------------------------------------------
// Fused preprocessing: x->hi|lo, Wq->hi|lo, Wk->hi|lo, Wv->f16, Wo->f16,
// bias concat [bq|bk].
// ---------------------------------------------------------------------------
__global__ __launch_bounds__(256) void prep(
    const float* __restrict__ x,  const float* __restrict__ Wq,
    const float* __restrict__ Wk, const float* __restrict__ Wv,
    const float* __restrict__ Wo, const float* __restrict__ bq,
    const float* __restrict__ bk,
    _Float16* __restrict__ x2,  _Float16* __restrict__ w2q,
    _Float16* __restrict__ w2k, _Float16* __restrict__ wv16,
    _Float16* __restrict__ wo16, float* __restrict__ bqk) {
    const int bid = blockIdx.x;
    if (bid < 5120) {           // split jobs: x / Wq / Wk
        const float* src; _Float16* dst; int t;
        if (bid < 4096)      { src = x;  dst = x2;  t = bid * 256 + threadIdx.x; }
        else if (bid < 4608) { src = Wq; dst = w2q; t = (bid - 4096) * 256 + threadIdx.x; }
        else                 { src = Wk; dst = w2k; t = (bid - 4608) * 256 + threadIdx.x; }
        int m = t >> 7, kc = (t & 127) << 3;
        const float* s = src + (size_t)m * 1024 + kc;
        f32x4 a = *(const f32x4*)s;
        f32x4 b = *(const f32x4*)(s + 4);
        float xs[8] = {a.x, a.y, a.z, a.w, b.x, b.y, b.z, b.w};
        half8 hi, lo;
        #pragma unroll
        for (int u = 0; u < 8; ++u) {
            _Float16 h = (_Float16)xs[u];
            hi[u] = h;
            lo[u] = (_Float16)(xs[u] - (float)h);
        }
        *(half8*)(dst + (size_t)m * 2048 + kc)        = hi;
        *(half8*)(dst + (size_t)m * 2048 + 1024 + kc) = lo;
    } else if (bid < 6144) {    // conv jobs: Wv / Wo
        const float* src; _Float16* dst; int t;
        if (bid < 5632) { src = Wv; dst = wv16; t = (bid - 5120) * 256 + threadIdx.x; }
        else            { src = Wo; dst = wo16; t = (bid - 5632) * 256 + threadIdx.x; }
        int m = t >> 7, kc = (t & 127) << 3;
        const float* s = src + (size_t)m * 1024 + kc;
        f32x4 a = *(const f32x4*)s;
        f32x4 b = *(const f32x4*)(s + 4);
        float xs[8] = {a.x, a.y, a.z, a.w, b.x, b.y, b.z, b.w};
        half8 hv;
        #pragma unroll
        for (int u = 0; u < 8; ++u) hv[u] = (_Float16)xs[u];
        *(half8*)(dst + (size_t)m * 1024 + kc) = hv;
    } else {
        int i = (bid - 6144) * 256 + threadIdx.x;
        bqk[i] = (i < 1024) ? bq[i] : bk[i - 1024];
    }
}

// ---------------------------------------------------------------------------
// Fused q/k/v projection GEMM (R5 structure, session plateau ~733 TF).
// R7: qk K-loop cut 96 -> 64 steps: hi*hi + lo*hi only (drop x_hi*W_lo).
// Residual q/k error ~= eps_W(f16 cast) -- strictly smaller than the v
// projection's eps_x+eps_W single-pass error, which has passed all session.
// den stays exact: qlo/klo residuals are relative to the COMPUTED vv.
// ---------------------------------------------------------------------------
__global__ __launch_bounds__(256, 4) void gemm_qkv(
    const _Float16* __restrict__ A,    // x2, lda 2048
    const _Float16* __restrict__ Bqk,  // [w2q;w2k], ldb 2048
    const _Float16* __restrict__ Bv,   // wv16, ldb 1024
    const float* __restrict__ bqk, const float* __restrict__ bv,
    _Float16* __restrict__ Qlo, _Float16* __restrict__ Klo,
    _Float16* __restrict__ Q16, _Float16* __restrict__ K16,
    _Float16* __restrict__ V16, float* __restrict__ ksum) {
    // two buffers of [A 128x32 | B 128x32] = 16KB each; slab reuses sbuf.
    __shared__ __align__(16) _Float16 sbuf[2 * 8192];
    __shared__ float sksum[2][128];
    _Float16* sC16 = sbuf;              // epilogue slab (needs 4352h <= 8192h)

    const int cb   = blockIdx.y;
    const int isqk = (cb < 16);
    const int isk  = (cb >= 8 && cb < 16);
    const int tid  = threadIdx.x;
    const int lane = tid & 63;
    const int w    = tid >> 6;
    const int row0 = blockIdx.x * 128;
    const int col0 = cb * 128;               // 0..3071 global col space
    const int wm   = (w & 1) * 64;
    const int wn   = (w >> 1) * 64;

    const _Float16* B = isqk ? Bqk : Bv;
    const int ldb     = isqk ? 2048 : 1024;
    const int bcol0   = isqk ? col0 : col0 - 2048;
    const int kits    = isqk ? 64 : 32;   // 64: K = [x_hi|x_lo] x W_hi

    const int ch0 = w * 64 + lane;
    const int rS0 = ch0 >> 2;
    const int cS0 = (ch0 & 3) ^ ((rS0 >> 1) & 3);
    const int ch1 = ch0 + 256;
    const int rS1 = ch1 >> 2;
    const int cS1 = (ch1 & 3) ^ ((rS1 >> 1) & 3);

    const _Float16* gA0 = A + (size_t)(row0  + rS0) * 2048 + cS0 * 8;
    const _Float16* gA1 = A + (size_t)(row0  + rS1) * 2048 + cS1 * 8;
    const _Float16* gB0 = B + (size_t)(bcol0 + rS0) * ldb  + cS0 * 8;
    const _Float16* gB1 = B + (size_t)(bcol0 + rS1) * ldb  + cS1 * 8;

    auto stage = [&](int kt, int bsel) {
        const int k0   = kt * 32;
        const int acol = k0;                           // 0..2047 (hi|lo of x)
        const int bcol = (k0 < 1024) ? k0 : k0 - 1024; // W hi cols only
        _Float16* l = sbuf + bsel * 8192;
        gld_lds16(gA0 + acol, l + w * 512);
        gld_lds16(gA1 + acol, l + 2048 + w * 512);
        gld_lds16(gB0 + bcol, l + 4096 + w * 512);
        gld_lds16(gB1 + bcol, l + 6144 + w * 512);
    };

    f32x4 acc[4][4];
    #pragma unroll
    for (int i = 0; i < 4; ++i)
        #pragma unroll
        for (int j = 0; j < 4; ++j) { f32x4 z = {0.f, 0.f, 0.f, 0.f}; acc[i][j] = z; }

    const int ml = lane & 15;
    const int kg = lane >> 4;
    int offA[4], offB[4];
    #pragma unroll
    for (int i = 0; i < 4; ++i) {
        int r  = wm + i * 16 + ml;
        offA[i] = r * 32 + (kg ^ ((r >> 1) & 3)) * 8;
        int rn = wn + i * 16 + ml;
        offB[i] = 4096 + rn * 32 + (kg ^ ((rn >> 1) & 3)) * 8;
    }

    stage(0, 0);
    asm volatile("s_waitcnt vmcnt(0)\n\ts_barrier" ::: "memory");
    int cur = 0;
    for (int t = 0; t < kits; ++t) {
        if (t + 1 < kits) stage(t + 1, cur ^ 1);   // issue BEFORE compute
        const _Float16* lb = sbuf + cur * 8192;
        half8 af[4], bf[4];
        #pragma unroll
        for (int i = 0; i < 4; ++i) {
            af[i] = *(const half8*)&lb[offA[i]];
            bf[i] = *(const half8*)&lb[offB[i]];
        }
        __builtin_amdgcn_s_setprio(1);
        #pragma unroll
        for (int i = 0; i < 4; ++i)
            #pragma unroll
            for (int j = 0; j < 4; ++j)
                acc[i][j] = __builtin_amdgcn_mfma_f32_16x16x32_f16(af[i], bf[j], acc[i][j], 0, 0, 0);
        __builtin_amdgcn_s_setprio(0);
        asm volatile("s_waitcnt vmcnt(0)\n\ts_barrier" ::: "memory");
        cur ^= 1;
    }

    // output routing
    const int colq = isqk ? ((col0 < 1024) ? col0 : col0 - 1024) : (col0 - 2048);
    _Float16* Ylo  = (col0 < 1024) ? Qlo : Klo;      // only used when isqk
    _Float16* Y16  = isqk ? ((col0 < 1024) ? Q16 : K16) : V16;

    const int rg = lane >> 4;
    #pragma unroll
    for (int j = 0; j < 4; ++j) {
        const float bvb = isqk ? bqk[col0 + wn + j * 16 + ml]
                               : bv[colq + wn + j * 16 + ml];
        const int nn = colq + wn + j * 16 + ml;
        #pragma unroll
        for (int i = 0; i < 4; ++i) {
            #pragma unroll
            for (int t = 0; t < 4; ++t) {
                float vv = acc[i][j][t] + bvb;
                if (isqk) {
                    vv = vv / (1.f + expf(-vv));     // silu
                    int mm = row0 + wm + i * 16 + rg * 4 + t;
                    _Float16 hv = (_Float16)vv;      // hi (same cast as slab)
                    Ylo[(size_t)mm * 1024 + nn] = (_Float16)(vv - (float)hv);
                }
                acc[i][j][t] = vv;
            }
        }
    }

    // fused ksum for k-blocks: this tile = chunk (b,n) x 2 heads.
    if (isk) {
        #pragma unroll
        for (int j = 0; j < 4; ++j) {
            float ps = 0.f;
            #pragma unroll
            for (int i = 0; i < 4; ++i)
                #pragma unroll
                for (int t = 0; t < 4; ++t) ps += acc[i][j][t];
            // reduce over the 4 rg lane groups (lanes kg*16+ml)
            ps += __shfl_xor(ps, 16, 64);
            ps += __shfl_xor(ps, 32, 64);
            if (kg == 0) sksum[wm >> 6][wn + j * 16 + ml] = ps;
        }
        __syncthreads();
        if (tid < 128) {
            const int b = row0 >> 11;
            const int n = (row0 >> 7) & 15;
            const int cg = colq + tid;         // global k-col
            const int h = cg >> 6, f = cg & 63;
            ksum[(size_t)(((b * 16 + h) * 16 + n)) * 64 + f] =
                sksum[0][tid] + sksum[1][tid];
        }
        __syncthreads();
    }

    // f16 via LDS slab transpose (4 slabs of 32 rows), slab buffer = sbuf
    for (int s = 0; s < 4; ++s) {
        if ((wm == 0) == (s < 2)) {
            const int ib = (s & 1) * 2;
            #pragma unroll
            for (int ii = 0; ii < 2; ++ii)
                #pragma unroll
                for (int j = 0; j < 4; ++j)
                    #pragma unroll
                    for (int t = 0; t < 4; ++t) {
                        int lr = ii * 16 + rg * 4 + t;
                        sC16[lr * 136 + wn + j * 16 + ml] = (_Float16)acc[ib + ii][j][t];
                    }
        }
        __syncthreads();
        #pragma unroll
        for (int u = 0; u < 2; ++u) {
            int c = u * 256 + tid;
            int r = c >> 4, cc = (c & 15) * 8;
            half8 hv = *(const half8*)&sC16[r * 136 + cc];
            *(half8*)(Y16 + (size_t)(row0 + 32 * s + r) * 1024 + colq + cc) = hv;
        }
        __syncthreads();
    }
}

// ---------------------------------------------------------------------------
// Final output GEMM: out = attn16 * wo16^T * 64 + bo. Tile 128x128, BK=32,
// 2-phase double buffer. grid dim3(64, 8).
// ---------------------------------------------------------------------------
__global__ __launch_bounds__(256, 4) void gemm_out(
    const _Float16* __restrict__ A,   // attn16, lda 1024
    const _Float16* __restrict__ B,   // wo16, ldb 1024
    const float* __restrict__ bias,
    float* __restrict__ Y) {
    __shared__ __align__(16) _Float16 sbuf[2 * 8192];  // [A 128x32 | B 128x32] x2

    const int tid  = threadIdx.x;
    const int lane = tid & 63;
    const int w    = tid >> 6;
    const int row0 = blockIdx.x * 128;
    const int col0 = blockIdx.y * 128;
    const int wm   = (w & 1) * 64;
    const int wn   = (w >> 1) * 64;

    const int ch0 = w * 64 + lane;
    const int rS0 = ch0 >> 2;
    const int cS0 = (ch0 & 3) ^ ((rS0 >> 1) & 3);
    const int ch1 = ch0 + 256;
    const int rS1 = ch1 >> 2;
    const int cS1 = (ch1 & 3) ^ ((rS1 >> 1) & 3);

    const _Float16* gA0 = A + (size_t)(row0 + rS0) * 1024 + cS0 * 8;
    const _Float16* gA1 = A + (size_t)(row0 + rS1) * 1024 + cS1 * 8;
    const _Float16* gB0 = B + (size_t)(col0 + rS0) * 1024 + cS0 * 8;
    const _Float16* gB1 = B + (size_t)(col0 + rS1) * 1024 + cS1 * 8;

    auto stage = [&](int kt, int bsel) {
        const int k0 = kt * 32;
        _Float16* l = sbuf + bsel * 8192;
        gld_lds16(gA0 + k0, l + w * 512);
        gld_lds16(gA1 + k0, l + 2048 + w * 512);
        gld_lds16(gB0 + k0, l + 4096 + w * 512);
        gld_lds16(gB1 + k0, l + 6144 + w * 512);
    };

    f32x4 acc[4][4];
    #pragma unroll
    for (int i = 0; i < 4; ++i)
        #pragma unroll
        for (int j = 0; j < 4; ++j) { f32x4 z = {0.f, 0.f, 0.f, 0.f}; acc[i][j] = z; }

    const int ml = lane & 15;
    const int kg = lane >> 4;
    int offA[4], offB[4];
    #pragma unroll
    for (int i = 0; i < 4; ++i) {
        int r  = wm + i * 16 + ml;
        offA[i] = r * 32 + (kg ^ ((r >> 1) & 3)) * 8;
        int rn = wn + i * 16 + ml;
        offB[i] = 4096 + rn * 32 + (kg ^ ((rn >> 1) & 3)) * 8;
    }

    stage(0, 0);
    asm volatile("s_waitcnt vmcnt(0)\n\ts_barrier" ::: "memory");
    int cur = 0;
    for (int kit = 0; kit < 32; ++kit) {
        if (kit + 1 < 32) stage(kit + 1, cur ^ 1);
        const _Float16* lb = sbuf + cur * 8192;
        half8 af[4], bf[4];
        #pragma unroll
        for (int i = 0; i < 4; ++i) {
            af[i] = *(const half8*)&lb[offA[i]];
            bf[i] = *(const half8*)&lb[offB[i]];
        }
        __builtin_amdgcn_s_setprio(1);
        #pragma unroll
        for (int i = 0; i < 4; ++i)
            #pragma unroll
            for (int j = 0; j < 4; ++j)
                acc[i][j] = __builtin_amdgcn_mfma_f32_16x16x32_f16(af[i], bf[j], acc[i][j], 0, 0, 0);
        __builtin_amdgcn_s_setprio(0);
        asm volatile("s_waitcnt vmcnt(0)\n\ts_barrier" ::: "memory");
        cur ^= 1;
    }

    const int rg = lane >> 4;
    #pragma unroll
    for (int j = 0; j < 4; ++j) {
        const int nn = col0 + wn + j * 16 + ml;
        const float bvb = bias[nn];
        #pragma unroll
        for (int i = 0; i < 4; ++i) {
            #pragma unroll
            for (int t = 0; t < 4; ++t) {
                int mm = row0 + wm + i * 16 + rg * 4 + t;
                Y[(size_t)mm * 1024 + nn] = acc[i][j][t] * 64.f + bvb;
            }
        }
    }
}

// ---------------------------------------------------------------------------
// chunk stats: kvT[blk][e][f] = sum_j v16[j][e]*k16[j][f] via MFMA.
// ---------------------------------------------------------------------------
__global__ __launch_bounds__(256) void chunk_stats(
    const _Float16* __restrict__ k16g, const _Float16* __restrict__ v16g,
    float* __restrict__ kvT) {
    const int blk = blockIdx.x;
    const int n = blk & 15, bh = blk >> 4, h = bh & 15, b = bh >> 4;
    const size_t base = ((size_t)b * L_SEQ + (size_t)n * CHUNK) * D_MODEL + (size_t)h * HDIM;

    __shared__ __align__(16) _Float16 sv[64 * 136];
    __shared__ __align__(16) _Float16 sk[64 * 136];

    const int tid = threadIdx.x;
    #pragma unroll
    for (int p = 0; p < 4; ++p) {
        int idx = p * 256 + tid;
        int j = idx >> 3, c = idx & 7;
        half8 vv = *(const half8*)(v16g + base + (size_t)j * D_MODEL + c * 8);
        half8 kk = *(const half8*)(k16g + base + (size_t)j * D_MODEL + c * 8);
        #pragma unroll
        for (int u = 0; u < 8; ++u) {
            sv[(c * 8 + u) * 136 + j] = vv[u];
            sk[(c * 8 + u) * 136 + j] = kk[u];
        }
    }
    __syncthreads();

    const int lane = tid & 63;
    const int w    = tid >> 6;
    const int ml   = lane & 15;
    const int kg   = lane >> 4;

    f32x4 acc[4];
    #pragma unroll
    for (int ft = 0; ft < 4; ++ft) { f32x4 z = {0.f,0.f,0.f,0.f}; acc[ft] = z; }
    #pragma unroll
    for (int ft = 0; ft < 4; ++ft)
        #pragma unroll
        for (int kit = 0; kit < 4; ++kit) {
            half8 af = *(const half8*)&sv[(w * 16 + ml) * 136 + kit * 32 + kg * 8];
            half8 bf = *(const half8*)&sk[(ft * 16 + ml) * 136 + kit * 32 + kg * 8];
            acc[ft] = __builtin_amdgcn_mfma_f32_16x16x32_f16(af, bf, acc[ft], 0, 0, 0);
        }
    float* o = kvT + (size_t)blk * 4096;
    #pragma unroll
    for (int ft = 0; ft < 4; ++ft)
        #pragma unroll
        for (int t = 0; t < 4; ++t) {
            int e = w * 16 + kg * 4 + t;
            o[e * 64 + ft * 16 + ml] = acc[ft][t];
        }
}

// ---------------------------------------------------------------------------
// Exclusive cumsum over chunk axis; emits prefix directly as f16.
// ---------------------------------------------------------------------------
__global__ __launch_bounds__(256) void scan_chunks(const float* __restrict__ kvT,
                                                   _Float16* __restrict__ kv16,
                                                   float* __restrict__ ksum) {
    const int bh  = blockIdx.x >> 4;
    const int seg = blockIdx.x & 15;
    const int idx = seg * 256 + threadIdx.x;
    const float* base = kvT + (size_t)bh * NCHUNK * 4096 + idx;
    _Float16*   obase = kv16 + (size_t)bh * NCHUNK * 4096 + idx;
    float run = 0.f;
    #pragma unroll
    for (int nn = 0; nn < NCHUNK; ++nn) {
        float t = base[(size_t)nn * 4096];
        obase[(size_t)nn * 4096] = (_Float16)run;
        run += t;
    }
    if (seg == 0 && threadIdx.x < 64) {
        float* zb = ksum + (size_t)bh * NCHUNK * 64 + threadIdx.x;
        float r2 = 0.f;
        #pragma unroll
        for (int nn = 0; nn < NCHUNK; ++nn) {
            float t = zb[nn * 64];
            zb[nn * 64] = r2;
            r2 += t;
        }
    }
}

// ---------------------------------------------------------------------------
// MFMA attention core with fused fp32-grade denominator (unchanged from R6).
// ---------------------------------------------------------------------------
__global__ __launch_bounds__(256) void attn_core(
    const _Float16* __restrict__ q16g, const _Float16* __restrict__ k16g,
    const _Float16* __restrict__ v16g, const _Float16* __restrict__ qlog,
    const _Float16* __restrict__ klog, const _Float16* __restrict__ ST16,
    const float* __restrict__ zg, _Float16* __restrict__ O16) {
    const int blk = blockIdx.x;
    const int n = blk & 15, bh = blk >> 4, h = bh & 15, b = bh >> 4;
    const size_t base = ((size_t)b * L_SEQ + (size_t)n * CHUNK) * D_MODEL + (size_t)h * HDIM;

    __shared__ __align__(16) _Float16 sq [128 * 72];
    __shared__ __align__(16) _Float16 sk [128 * 72];
    __shared__ __align__(16) _Float16 sv [64 * 136];
    __shared__ __align__(16) _Float16 sS [64 * 72];
    __shared__ __align__(16) _Float16 ssc[64 * 136];   // 8704h; doubles as klo stage
    __shared__ float szz[64];
    _Float16* sklo = ssc;   // klo[j][chunk c] at j*64 + ((c^(j&7))<<3); 8192h

    const int tid = threadIdx.x;
    #pragma unroll
    for (int p = 0; p < 4; ++p) {
        int idx = p * 256 + tid;
        int j = idx >> 3, c = idx & 7;
        *(half8*)&sq[j * 72 + c * 8] = *(const half8*)(q16g + base + (size_t)j * D_MODEL + c * 8);
        *(half8*)&sk[j * 72 + c * 8] = *(const half8*)(k16g + base + (size_t)j * D_MODEL + c * 8);
        half8 vv = *(const half8*)(v16g + base + (size_t)j * D_MODEL + c * 8);
        #pragma unroll
        for (int u = 0; u < 8; ++u) sv[(c * 8 + u) * 136 + j] = vv[u];
        half8 kl = *(const half8*)(klog + base + (size_t)j * D_MODEL + c * 8);
        *(half8*)&sklo[j * 64 + ((c ^ (j & 7)) << 3)] = kl;
    }
    #pragma unroll
    for (int p = 0; p < 2; ++p) {
        int idx = p * 256 + tid;
        int e = idx >> 3, c = idx & 7;
        *(half8*)&sS[e * 72 + c * 8] =
            *(const half8*)(ST16 + (size_t)blk * 4096 + e * 64 + c * 8);
    }
    if (tid < 64) szz[tid] = zg[(size_t)blk * 64 + tid];
    __syncthreads();

    const int lane = tid & 63;
    const int w    = tid >> 6;
    const int ml   = lane & 15;
    const int kg   = lane >> 4;

    // ---- QK^T (hi*hi + hi*lo + lo*hi) for BOTH row-halves, klo from LDS ----
    f32x4 acc1a[8], acc1b[8];
    #pragma unroll
    for (int nt = 0; nt < 8; ++nt) {
        f32x4 z = {0.f,0.f,0.f,0.f}; acc1a[nt] = z; acc1b[nt] = z;
    }

    auto qk_acc = [&](f32x4 (&a1)[8], int r0) {
        const int rowmax = r0 + 15;
        half8 aflo0 = *(const half8*)(qlog + base + (size_t)(r0 + ml) * D_MODEL + kg * 8);
        half8 aflo1 = *(const half8*)(qlog + base + (size_t)(r0 + ml) * D_MODEL + 32 + kg * 8);
        #pragma unroll
        for (int nt = 0; nt < 8; ++nt) {
            if (nt * 16 <= rowmax) {
                #pragma unroll
                for (int kit = 0; kit < 2; ++kit) {
                    half8 af = *(const half8*)&sq[(r0 + ml) * 72 + kit * 32 + kg * 8];
                    half8 bf = *(const half8*)&sk[(nt * 16 + ml) * 72 + kit * 32 + kg * 8];
                    a1[nt] = __builtin_amdgcn_mfma_f32_16x16x32_f16(af, bf, a1[nt], 0, 0, 0);
                }
            }
        }
        #pragma unroll
        for (int nt = 0; nt < 8; ++nt) {
            if (nt * 16 <= rowmax) {
                const int jr = nt * 16 + ml;
                half8 bl0 = *(const half8*)&sklo[jr * 64 + ((kg ^ (jr & 7)) << 3)];
                half8 bl1 = *(const half8*)&sklo[jr * 64 + (((4 + kg) ^ (jr & 7)) << 3)];
                half8 ah0 = *(const half8*)&sq[(r0 + ml) * 72 + kg * 8];
                half8 ah1 = *(const half8*)&sq[(r0 + ml) * 72 + 32 + kg * 8];
                half8 bh0 = *(const half8*)&sk[jr * 72 + kg * 8];
                half8 bh1 = *(const half8*)&sk[jr * 72 + 32 + kg * 8];
                a1[nt] = __builtin_amdgcn_mfma_f32_16x16x32_f16(ah0, bl0, a1[nt], 0, 0, 0);
                a1[nt] = __builtin_amdgcn_mfma_f32_16x16x32_f16(ah1, bl1, a1[nt], 0, 0, 0);
                a1[nt] = __builtin_amdgcn_mfma_f32_16x16x32_f16(aflo0, bh0, a1[nt], 0, 0, 0);
                a1[nt] = __builtin_amdgcn_mfma_f32_16x16x32_f16(aflo1, bh1, a1[nt], 0, 0, 0);
            }
        }
    };
    qk_acc(acc1a, w * 16);
    qk_acc(acc1b, 64 + w * 16);
    __syncthreads();   // all waves done reading sklo (=ssc) before S overwrite

    // ---- per-half: den, masked-S to LDS, PV + qS, store ----
    auto finish = [&](f32x4 (&a1)[8], int h2, int nkit) {
        const int r0 = h2 * 64 + w * 16;
        float rs[4];
        #pragma unroll
        for (int t = 0; t < 4; ++t) {
            const int ig = r0 + kg * 4 + t;
            float s = 0.f;
            #pragma unroll
            for (int nt = 0; nt < 8; ++nt) {
                int jg = nt * 16 + ml;
                s += (jg <= ig) ? a1[nt][t] : 0.f;
            }
            const int f0 = ml * 4;
            half4 ql = *(const half4*)(qlog + base + (size_t)ig * D_MODEL + f0);
            #pragma unroll
            for (int u = 0; u < 4; ++u)
                s += ((float)sq[ig * 72 + f0 + u] + (float)ql[u]) * szz[f0 + u];
            s += __shfl_xor(s, 1, 64);
            s += __shfl_xor(s, 2, 64);
            s += __shfl_xor(s, 4, 64);
            s += __shfl_xor(s, 8, 64);
            rs[t] = s;
        }

        #pragma unroll
        for (int nt = 0; nt < 8; ++nt) {
            #pragma unroll
            for (int t = 0; t < 4; ++t) {
                int lr = w * 16 + kg * 4 + t;
                int ig = h2 * 64 + lr;
                int jg = nt * 16 + ml;
                float val = (jg <= ig) ? a1[nt][t] : 0.f;
                ssc[lr * 136 + jg] = (_Float16)val;
            }
        }
        __syncthreads();

        f32x4 acc2[4];
        #pragma unroll
        for (int et = 0; et < 4; ++et) { f32x4 z = {0.f,0.f,0.f,0.f}; acc2[et] = z; }
        #pragma unroll
        for (int et = 0; et < 4; ++et) {
            for (int kit = 0; kit < nkit; ++kit) {
                half8 af = *(const half8*)&ssc[(w * 16 + ml) * 136 + kit * 32 + kg * 8];
                half8 bf = *(const half8*)&sv[(et * 16 + ml) * 136 + kit * 32 + kg * 8];
                acc2[et] = __builtin_amdgcn_mfma_f32_16x16x32_f16(af, bf, acc2[et], 0, 0, 0);
            }
            #pragma unroll
            for (int kit = 0; kit < 2; ++kit) {
                half8 af = *(const half8*)&sq[(r0 + ml) * 72 + kit * 32 + kg * 8];
                half8 bf = *(const half8*)&sS[(et * 16 + ml) * 72 + kit * 32 + kg * 8];
                acc2[et] = __builtin_amdgcn_mfma_f32_16x16x32_f16(af, bf, acc2[et], 0, 0, 0);
            }
        }
        #pragma unroll
        for (int t = 0; t < 4; ++t) {
            int lr = w * 16 + kg * 4 + t;
            int ig = h2 * 64 + lr;
            float rc = 0.015625f / fmaxf(rs[t], EPS_DEN);
            #pragma unroll
            for (int et = 0; et < 4; ++et) {
                int e = et * 16 + ml;
                O16[base + (size_t)ig * D_MODEL + e] = (_Float16)(acc2[et][t] * rc);
            }
        }
        __syncthreads();
    };
    finish(acc1a, 0, 2);
    finish(acc1b, 1, 4);
}

// ---------------------------------------------------------------------------
extern "C" void kernel_launch(void* const* d_in, const int* in_sizes, int n_in,
                              void* d_out, int out_size, void* d_ws, size_t ws_size,
                              hipStream_t stream) {
    const float* x  = (const float*)d_in[0];
    const float* Wq = (const float*)d_in[1];
    const float* bq = (const float*)d_in[2];
    const float* Wk = (const float*)d_in[3];
    const float* bk = (const float*)d_in[4];
    const float* Wv = (const float*)d_in[5];
    const float* bv = (const float*)d_in[6];
    const float* Wo = (const float*)d_in[7];
    const float* bo = (const float*)d_in[8];
    float* out = (float*)d_out;

    char* p = (char*)d_ws;
    _Float16* x2   = (_Float16*)p;  p += (size_t)NTOK * 2048 * 2;
    _Float16* w2q  = (_Float16*)p;  p += (size_t)1024 * 2048 * 2;
    _Float16* w2k  = (_Float16*)p;  p += (size_t)1024 * 2048 * 2;   // contiguous after w2q
    _Float16* wv16 = (_Float16*)p;  p += (size_t)1024 * 1024 * 2;
    _Float16* wo16 = (_Float16*)p;  p += (size_t)1024 * 1024 * 2;
    _Float16* qlo  = (_Float16*)p;  p += (size_t)NTOK * 1024 * 2;
    _Float16* klo  = (_Float16*)p;  p += (size_t)NTOK * 1024 * 2;
    _Float16* q16  = (_Float16*)p;  p += (size_t)NTOK * 1024 * 2;
    _Float16* k16  = (_Float16*)p;  p += (size_t)NTOK * 1024 * 2;
    _Float16* v16  = (_Float16*)p;  p += (size_t)NTOK * 1024 * 2;
    float* kvT  = (float*)p;        p += (size_t)1024 * 4096 * 4;
    _Float16* kv16 = (_Float16*)p;  p += (size_t)1024 * 4096 * 2;
    float* ksb  = (float*)p;        p += (size_t)1024 * 64 * 4;
    float* bqk  = (float*)p;        p += 2048 * 4;
    _Float16* attn16 = x2;  // x2 dead after gemm_qkv

    prep<<<6152, 256, 0, stream>>>(x, Wq, Wk, Wv, Wo, bq, bk,
                                   x2, w2q, w2k, wv16, wo16, bqk);

    gemm_qkv<<<dim3(64, 24), 256, 0, stream>>>(x2, w2q, wv16, bqk, bv,
                                               qlo, klo, q16, k16, v16, ksb);

    chunk_stats<<<1024, 256, 0, stream>>>(k16, v16, kvT);
    scan_chunks<<<1024, 256, 0, stream>>>(kvT, kv16, ksb);
    attn_core<<<1024, 256, 0, stream>>>(q16, k16, v16, qlo, klo, kv16, ksb, attn16);

    gemm_out<<<dim3(64, 8), 256, 0, stream>>>(attn16, wo16, bo, out);
}

// Round 8
// 294.020 us; speedup vs baseline: 1.2100x; 1.0051x over previous
//
#include <hip/hip_runtime.h>
#include <math.h>

#define D_MODEL 1024
#define HEADS   16
#define HDIM    64
#define CHUNK   128
#define B_SZ    4
#define L_SEQ   2048
#define NCHUNK  16
#define NTOK    8192
#define EPS_DEN 1e-3f

typedef _Float16 half8 __attribute__((ext_vector_type(8)));
typedef _Float16 half4 __attribute__((ext_vector_type(4)));
typedef float    f32x4 __attribute__((ext_vector_type(4)));

__device__ __forceinline__ void gld_lds16(const void* g, void* l) {
    __builtin_amdgcn_global_load_lds(
        (const __attribute__((address_space(1))) void*)g,
        (__attribute__((address_space(3))) void*)l, 16, 0, 0);
}

// ---------------------------------------------------------------------------
// Fused preprocessing: x->hi|lo, Wq->hi|lo, Wk->hi|lo, Wv->f16, Wo->f16,
// bias concat [bq|bk].
// ---------------------------------------------------------------------------
__global__ __launch_bounds__(256) void prep(
    const float* __restrict__ x,  const float* __restrict__ Wq,
    const float* __restrict__ Wk, const float* __restrict__ Wv,
    const float* __restrict__ Wo, const float* __restrict__ bq,
    const float* __restrict__ bk,
    _Float16* __restrict__ x2,  _Float16* __restrict__ w2q,
    _Float16* __restrict__ w2k, _Float16* __restrict__ wv16,
    _Float16* __restrict__ wo16, float* __restrict__ bqk) {
    const int bid = blockIdx.x;
    if (bid < 5120) {           // split jobs: x / Wq / Wk
        const float* src; _Float16* dst; int t;
        if (bid < 4096)      { src = x;  dst = x2;  t = bid * 256 + threadIdx.x; }
        else if (bid < 4608) { src = Wq; dst = w2q; t = (bid - 4096) * 256 + threadIdx.x; }
        else                 { src = Wk; dst = w2k; t = (bid - 4608) * 256 + threadIdx.x; }
        int m = t >> 7, kc = (t & 127) << 3;
        const float* s = src + (size_t)m * 1024 + kc;
        f32x4 a = *(const f32x4*)s;
        f32x4 b = *(const f32x4*)(s + 4);
        float xs[8] = {a.x, a.y, a.z, a.w, b.x, b.y, b.z, b.w};
        half8 hi, lo;
        #pragma unroll
        for (int u = 0; u < 8; ++u) {
            _Float16 h = (_Float16)xs[u];
            hi[u] = h;
            lo[u] = (_Float16)(xs[u] - (float)h);
        }
        *(half8*)(dst + (size_t)m * 2048 + kc)        = hi;
        *(half8*)(dst + (size_t)m * 2048 + 1024 + kc) = lo;
    } else if (bid < 6144) {    // conv jobs: Wv / Wo
        const float* src; _Float16* dst; int t;
        if (bid < 5632) { src = Wv; dst = wv16; t = (bid - 5120) * 256 + threadIdx.x; }
        else            { src = Wo; dst = wo16; t = (bid - 5632) * 256 + threadIdx.x; }
        int m = t >> 7, kc = (t & 127) << 3;
        const float* s = src + (size_t)m * 1024 + kc;
        f32x4 a = *(const f32x4*)s;
        f32x4 b = *(const f32x4*)(s + 4);
        float xs[8] = {a.x, a.y, a.z, a.w, b.x, b.y, b.z, b.w};
        half8 hv;
        #pragma unroll
        for (int u = 0; u < 8; ++u) hv[u] = (_Float16)xs[u];
        *(half8*)(dst + (size_t)m * 1024 + kc) = hv;
    } else {
        int i = (bid - 6144) * 256 + threadIdx.x;
        bqk[i] = (i < 1024) ? bq[i] : bk[i - 1024];
    }
}

// ---------------------------------------------------------------------------
// Fused q/k/v projection GEMM (R7: qk K = [x_hi|x_lo] x W_hi, 64 steps).
// ---------------------------------------------------------------------------
__global__ __launch_bounds__(256, 4) void gemm_qkv(
    const _Float16* __restrict__ A,    // x2, lda 2048
    const _Float16* __restrict__ Bqk,  // [w2q;w2k], ldb 2048
    const _Float16* __restrict__ Bv,   // wv16, ldb 1024
    const float* __restrict__ bqk, const float* __restrict__ bv,
    _Float16* __restrict__ Qlo, _Float16* __restrict__ Klo,
    _Float16* __restrict__ Q16, _Float16* __restrict__ K16,
    _Float16* __restrict__ V16, float* __restrict__ ksum) {
    // two buffers of [A 128x32 | B 128x32] = 16KB each; slab reuses sbuf.
    __shared__ __align__(16) _Float16 sbuf[2 * 8192];
    __shared__ float sksum[2][128];
    _Float16* sC16 = sbuf;              // epilogue slab (needs 4352h <= 8192h)

    const int cb   = blockIdx.y;
    const int isqk = (cb < 16);
    const int isk  = (cb >= 8 && cb < 16);
    const int tid  = threadIdx.x;
    const int lane = tid & 63;
    const int w    = tid >> 6;
    const int row0 = blockIdx.x * 128;
    const int col0 = cb * 128;               // 0..3071 global col space
    const int wm   = (w & 1) * 64;
    const int wn   = (w >> 1) * 64;

    const _Float16* B = isqk ? Bqk : Bv;
    const int ldb     = isqk ? 2048 : 1024;
    const int bcol0   = isqk ? col0 : col0 - 2048;
    const int kits    = isqk ? 64 : 32;   // 64: K = [x_hi|x_lo] x W_hi

    const int ch0 = w * 64 + lane;
    const int rS0 = ch0 >> 2;
    const int cS0 = (ch0 & 3) ^ ((rS0 >> 1) & 3);
    const int ch1 = ch0 + 256;
    const int rS1 = ch1 >> 2;
    const int cS1 = (ch1 & 3) ^ ((rS1 >> 1) & 3);

    const _Float16* gA0 = A + (size_t)(row0  + rS0) * 2048 + cS0 * 8;
    const _Float16* gA1 = A + (size_t)(row0  + rS1) * 2048 + cS1 * 8;
    const _Float16* gB0 = B + (size_t)(bcol0 + rS0) * ldb  + cS0 * 8;
    const _Float16* gB1 = B + (size_t)(bcol0 + rS1) * ldb  + cS1 * 8;

    auto stage = [&](int kt, int bsel) {
        const int k0   = kt * 32;
        const int acol = k0;                           // 0..2047 (hi|lo of x)
        const int bcol = (k0 < 1024) ? k0 : k0 - 1024; // W hi cols only
        _Float16* l = sbuf + bsel * 8192;
        gld_lds16(gA0 + acol, l + w * 512);
        gld_lds16(gA1 + acol, l + 2048 + w * 512);
        gld_lds16(gB0 + bcol, l + 4096 + w * 512);
        gld_lds16(gB1 + bcol, l + 6144 + w * 512);
    };

    f32x4 acc[4][4];
    #pragma unroll
    for (int i = 0; i < 4; ++i)
        #pragma unroll
        for (int j = 0; j < 4; ++j) { f32x4 z = {0.f, 0.f, 0.f, 0.f}; acc[i][j] = z; }

    const int ml = lane & 15;
    const int kg = lane >> 4;
    int offA[4], offB[4];
    #pragma unroll
    for (int i = 0; i < 4; ++i) {
        int r  = wm + i * 16 + ml;
        offA[i] = r * 32 + (kg ^ ((r >> 1) & 3)) * 8;
        int rn = wn + i * 16 + ml;
        offB[i] = 4096 + rn * 32 + (kg ^ ((rn >> 1) & 3)) * 8;
    }

    stage(0, 0);
    asm volatile("s_waitcnt vmcnt(0)\n\ts_barrier" ::: "memory");
    int cur = 0;
    for (int t = 0; t < kits; ++t) {
        if (t + 1 < kits) stage(t + 1, cur ^ 1);   // issue BEFORE compute
        const _Float16* lb = sbuf + cur * 8192;
        half8 af[4], bf[4];
        #pragma unroll
        for (int i = 0; i < 4; ++i) {
            af[i] = *(const half8*)&lb[offA[i]];
            bf[i] = *(const half8*)&lb[offB[i]];
        }
        __builtin_amdgcn_s_setprio(1);
        #pragma unroll
        for (int i = 0; i < 4; ++i)
            #pragma unroll
            for (int j = 0; j < 4; ++j)
                acc[i][j] = __builtin_amdgcn_mfma_f32_16x16x32_f16(af[i], bf[j], acc[i][j], 0, 0, 0);
        __builtin_amdgcn_s_setprio(0);
        asm volatile("s_waitcnt vmcnt(0)\n\ts_barrier" ::: "memory");
        cur ^= 1;
    }

    // output routing
    const int colq = isqk ? ((col0 < 1024) ? col0 : col0 - 1024) : (col0 - 2048);
    _Float16* Ylo  = (col0 < 1024) ? Qlo : Klo;      // only used when isqk
    _Float16* Y16  = isqk ? ((col0 < 1024) ? Q16 : K16) : V16;

    const int rg = lane >> 4;
    #pragma unroll
    for (int j = 0; j < 4; ++j) {
        const float bvb = isqk ? bqk[col0 + wn + j * 16 + ml]
                               : bv[colq + wn + j * 16 + ml];
        const int nn = colq + wn + j * 16 + ml;
        #pragma unroll
        for (int i = 0; i < 4; ++i) {
            #pragma unroll
            for (int t = 0; t < 4; ++t) {
                float vv = acc[i][j][t] + bvb;
                if (isqk) {
                    vv = vv / (1.f + expf(-vv));     // silu
                    int mm = row0 + wm + i * 16 + rg * 4 + t;
                    _Float16 hv = (_Float16)vv;      // hi (same cast as slab)
                    Ylo[(size_t)mm * 1024 + nn] = (_Float16)(vv - (float)hv);
                }
                acc[i][j][t] = vv;
            }
        }
    }

    // fused ksum for k-blocks: this tile = chunk (b,n) x 2 heads.
    if (isk) {
        #pragma unroll
        for (int j = 0; j < 4; ++j) {
            float ps = 0.f;
            #pragma unroll
            for (int i = 0; i < 4; ++i)
                #pragma unroll
                for (int t = 0; t < 4; ++t) ps += acc[i][j][t];
            // reduce over the 4 rg lane groups (lanes kg*16+ml)
            ps += __shfl_xor(ps, 16, 64);
            ps += __shfl_xor(ps, 32, 64);
            if (kg == 0) sksum[wm >> 6][wn + j * 16 + ml] = ps;
        }
        __syncthreads();
        if (tid < 128) {
            const int b = row0 >> 11;
            const int n = (row0 >> 7) & 15;
            const int cg = colq + tid;         // global k-col
            const int h = cg >> 6, f = cg & 63;
            ksum[(size_t)(((b * 16 + h) * 16 + n)) * 64 + f] =
                sksum[0][tid] + sksum[1][tid];
        }
        __syncthreads();
    }

    // f16 via LDS slab transpose (4 slabs of 32 rows), slab buffer = sbuf
    for (int s = 0; s < 4; ++s) {
        if ((wm == 0) == (s < 2)) {
            const int ib = (s & 1) * 2;
            #pragma unroll
            for (int ii = 0; ii < 2; ++ii)
                #pragma unroll
                for (int j = 0; j < 4; ++j)
                    #pragma unroll
                    for (int t = 0; t < 4; ++t) {
                        int lr = ii * 16 + rg * 4 + t;
                        sC16[lr * 136 + wn + j * 16 + ml] = (_Float16)acc[ib + ii][j][t];
                    }
        }
        __syncthreads();
        #pragma unroll
        for (int u = 0; u < 2; ++u) {
            int c = u * 256 + tid;
            int r = c >> 4, cc = (c & 15) * 8;
            half8 hv = *(const half8*)&sC16[r * 136 + cc];
            *(half8*)(Y16 + (size_t)(row0 + 32 * s + r) * 1024 + colq + cc) = hv;
        }
        __syncthreads();
    }
}

// ---------------------------------------------------------------------------
// Final output GEMM: out = attn16 * wo16^T * 64 + bo. Tile 128x128, BK=32,
// 2-phase double buffer. grid dim3(64, 8).
// ---------------------------------------------------------------------------
__global__ __launch_bounds__(256, 4) void gemm_out(
    const _Float16* __restrict__ A,   // attn16, lda 1024
    const _Float16* __restrict__ B,   // wo16, ldb 1024
    const float* __restrict__ bias,
    float* __restrict__ Y) {
    __shared__ __align__(16) _Float16 sbuf[2 * 8192];  // [A 128x32 | B 128x32] x2

    const int tid  = threadIdx.x;
    const int lane = tid & 63;
    const int w    = tid >> 6;
    const int row0 = blockIdx.x * 128;
    const int col0 = blockIdx.y * 128;
    const int wm   = (w & 1) * 64;
    const int wn   = (w >> 1) * 64;

    const int ch0 = w * 64 + lane;
    const int rS0 = ch0 >> 2;
    const int cS0 = (ch0 & 3) ^ ((rS0 >> 1) & 3);
    const int ch1 = ch0 + 256;
    const int rS1 = ch1 >> 2;
    const int cS1 = (ch1 & 3) ^ ((rS1 >> 1) & 3);

    const _Float16* gA0 = A + (size_t)(row0 + rS0) * 1024 + cS0 * 8;
    const _Float16* gA1 = A + (size_t)(row0 + rS1) * 1024 + cS1 * 8;
    const _Float16* gB0 = B + (size_t)(col0 + rS0) * 1024 + cS0 * 8;
    const _Float16* gB1 = B + (size_t)(col0 + rS1) * 1024 + cS1 * 8;

    auto stage = [&](int kt, int bsel) {
        const int k0 = kt * 32;
        _Float16* l = sbuf + bsel * 8192;
        gld_lds16(gA0 + k0, l + w * 512);
        gld_lds16(gA1 + k0, l + 2048 + w * 512);
        gld_lds16(gB0 + k0, l + 4096 + w * 512);
        gld_lds16(gB1 + k0, l + 6144 + w * 512);
    };

    f32x4 acc[4][4];
    #pragma unroll
    for (int i = 0; i < 4; ++i)
        #pragma unroll
        for (int j = 0; j < 4; ++j) { f32x4 z = {0.f, 0.f, 0.f, 0.f}; acc[i][j] = z; }

    const int ml = lane & 15;
    const int kg = lane >> 4;
    int offA[4], offB[4];
    #pragma unroll
    for (int i = 0; i < 4; ++i) {
        int r  = wm + i * 16 + ml;
        offA[i] = r * 32 + (kg ^ ((r >> 1) & 3)) * 8;
        int rn = wn + i * 16 + ml;
        offB[i] = 4096 + rn * 32 + (kg ^ ((rn >> 1) & 3)) * 8;
    }

    stage(0, 0);
    asm volatile("s_waitcnt vmcnt(0)\n\ts_barrier" ::: "memory");
    int cur = 0;
    for (int kit = 0; kit < 32; ++kit) {
        if (kit + 1 < 32) stage(kit + 1, cur ^ 1);
        const _Float16* lb = sbuf + cur * 8192;
        half8 af[4], bf[4];
        #pragma unroll
        for (int i = 0; i < 4; ++i) {
            af[i] = *(const half8*)&lb[offA[i]];
            bf[i] = *(const half8*)&lb[offB[i]];
        }
        __builtin_amdgcn_s_setprio(1);
        #pragma unroll
        for (int i = 0; i < 4; ++i)
            #pragma unroll
            for (int j = 0; j < 4; ++j)
                acc[i][j] = __builtin_amdgcn_mfma_f32_16x16x32_f16(af[i], bf[j], acc[i][j], 0, 0, 0);
        __builtin_amdgcn_s_setprio(0);
        asm volatile("s_waitcnt vmcnt(0)\n\ts_barrier" ::: "memory");
        cur ^= 1;
    }

    const int rg = lane >> 4;
    #pragma unroll
    for (int j = 0; j < 4; ++j) {
        const int nn = col0 + wn + j * 16 + ml;
        const float bvb = bias[nn];
        #pragma unroll
        for (int i = 0; i < 4; ++i) {
            #pragma unroll
            for (int t = 0; t < 4; ++t) {
                int mm = row0 + wm + i * 16 + rg * 4 + t;
                Y[(size_t)mm * 1024 + nn] = acc[i][j][t] * 64.f + bvb;
            }
        }
    }
}

// ---------------------------------------------------------------------------
// chunk stats: kvT[blk][e][f] = sum_j v16[j][e]*k16[j][f] via MFMA.
// ---------------------------------------------------------------------------
__global__ __launch_bounds__(256) void chunk_stats(
    const _Float16* __restrict__ k16g, const _Float16* __restrict__ v16g,
    float* __restrict__ kvT) {
    const int blk = blockIdx.x;
    const int n = blk & 15, bh = blk >> 4, h = bh & 15, b = bh >> 4;
    const size_t base = ((size_t)b * L_SEQ + (size_t)n * CHUNK) * D_MODEL + (size_t)h * HDIM;

    __shared__ __align__(16) _Float16 sv[64 * 136];
    __shared__ __align__(16) _Float16 sk[64 * 136];

    const int tid = threadIdx.x;
    #pragma unroll
    for (int p = 0; p < 4; ++p) {
        int idx = p * 256 + tid;
        int j = idx >> 3, c = idx & 7;
        half8 vv = *(const half8*)(v16g + base + (size_t)j * D_MODEL + c * 8);
        half8 kk = *(const half8*)(k16g + base + (size_t)j * D_MODEL + c * 8);
        #pragma unroll
        for (int u = 0; u < 8; ++u) {
            sv[(c * 8 + u) * 136 + j] = vv[u];
            sk[(c * 8 + u) * 136 + j] = kk[u];
        }
    }
    __syncthreads();

    const int lane = tid & 63;
    const int w    = tid >> 6;
    const int ml   = lane & 15;
    const int kg   = lane >> 4;

    f32x4 acc[4];
    #pragma unroll
    for (int ft = 0; ft < 4; ++ft) { f32x4 z = {0.f,0.f,0.f,0.f}; acc[ft] = z; }
    #pragma unroll
    for (int ft = 0; ft < 4; ++ft)
        #pragma unroll
        for (int kit = 0; kit < 4; ++kit) {
            half8 af = *(const half8*)&sv[(w * 16 + ml) * 136 + kit * 32 + kg * 8];
            half8 bf = *(const half8*)&sk[(ft * 16 + ml) * 136 + kit * 32 + kg * 8];
            acc[ft] = __builtin_amdgcn_mfma_f32_16x16x32_f16(af, bf, acc[ft], 0, 0, 0);
        }
    float* o = kvT + (size_t)blk * 4096;
    #pragma unroll
    for (int ft = 0; ft < 4; ++ft)
        #pragma unroll
        for (int t = 0; t < 4; ++t) {
            int e = w * 16 + kg * 4 + t;
            o[e * 64 + ft * 16 + ml] = acc[ft][t];
        }
}

// ---------------------------------------------------------------------------
// Exclusive cumsum over chunk axis; emits prefix directly as f16.
// ---------------------------------------------------------------------------
__global__ __launch_bounds__(256) void scan_chunks(const float* __restrict__ kvT,
                                                   _Float16* __restrict__ kv16,
                                                   float* __restrict__ ksum) {
    const int bh  = blockIdx.x >> 4;
    const int seg = blockIdx.x & 15;
    const int idx = seg * 256 + threadIdx.x;
    const float* base = kvT + (size_t)bh * NCHUNK * 4096 + idx;
    _Float16*   obase = kv16 + (size_t)bh * NCHUNK * 4096 + idx;
    float run = 0.f;
    #pragma unroll
    for (int nn = 0; nn < NCHUNK; ++nn) {
        float t = base[(size_t)nn * 4096];
        obase[(size_t)nn * 4096] = (_Float16)run;
        run += t;
    }
    if (seg == 0 && threadIdx.x < 64) {
        float* zb = ksum + (size_t)bh * NCHUNK * 64 + threadIdx.x;
        float r2 = 0.f;
        #pragma unroll
        for (int nn = 0; nn < NCHUNK; ++nn) {
            float t = zb[nn * 64];
            zb[nn * 64] = r2;
            r2 += t;
        }
    }
}

// ---------------------------------------------------------------------------
// MFMA attention core, 8-wave single-pass (R8).
// Wave w owns rows w*16..w*16+15 (was: 4 waves x 2 serial h2 halves).
// Same math, same per-accumulator MFMA order -> bit-identical results.
// Barriers 6 -> 3; resident waves/CU 4 -> 8 (LDS ~99KB, 1 block/CU).
// PV kit count per wave: (w>>1)+1 (dropped kits multiplied all-zero S).
// ---------------------------------------------------------------------------
__global__ __launch_bounds__(512) void attn_core(
    const _Float16* __restrict__ q16g, const _Float16* __restrict__ k16g,
    const _Float16* __restrict__ v16g, const _Float16* __restrict__ qlog,
    const _Float16* __restrict__ klog, const _Float16* __restrict__ ST16,
    const float* __restrict__ zg, _Float16* __restrict__ O16) {
    const int blk = blockIdx.x;
    const int n = blk & 15, bh = blk >> 4, h = bh & 15, b = bh >> 4;
    const size_t base = ((size_t)b * L_SEQ + (size_t)n * CHUNK) * D_MODEL + (size_t)h * HDIM;

    __shared__ __align__(16) _Float16 sq [128 * 72];
    __shared__ __align__(16) _Float16 sk [128 * 72];
    __shared__ __align__(16) _Float16 sv [64 * 136];
    __shared__ __align__(16) _Float16 sS [64 * 72];
    __shared__ __align__(16) _Float16 ssc[128 * 136];  // S stage; aliases klo stage
    __shared__ float szz[64];
    _Float16* sklo = ssc;   // klo[j][chunk c] at j*64 + ((c^(j&7))<<3); 8192h

    const int tid = threadIdx.x;
    #pragma unroll
    for (int p = 0; p < 2; ++p) {
        int idx = p * 512 + tid;
        int j = idx >> 3, c = idx & 7;
        *(half8*)&sq[j * 72 + c * 8] = *(const half8*)(q16g + base + (size_t)j * D_MODEL + c * 8);
        *(half8*)&sk[j * 72 + c * 8] = *(const half8*)(k16g + base + (size_t)j * D_MODEL + c * 8);
        half8 vv = *(const half8*)(v16g + base + (size_t)j * D_MODEL + c * 8);
        #pragma unroll
        for (int u = 0; u < 8; ++u) sv[(c * 8 + u) * 136 + j] = vv[u];
        half8 kl = *(const half8*)(klog + base + (size_t)j * D_MODEL + c * 8);
        *(half8*)&sklo[j * 64 + ((c ^ (j & 7)) << 3)] = kl;
    }
    {
        int e = tid >> 3, c = tid & 7;
        *(half8*)&sS[e * 72 + c * 8] =
            *(const half8*)(ST16 + (size_t)blk * 4096 + e * 64 + c * 8);
    }
    if (tid < 64) szz[tid] = zg[(size_t)blk * 64 + tid];
    __syncthreads();

    const int lane = tid & 63;
    const int w    = tid >> 6;          // 0..7, owns rows w*16..w*16+15
    const int ml   = lane & 15;
    const int kg   = lane >> 4;
    const int r0   = w * 16;
    const int rowmax = r0 + 15;

    // ---- QK^T: hi*hi + hi*lo + lo*hi (klo from LDS) ----
    f32x4 acc1[8];
    #pragma unroll
    for (int nt = 0; nt < 8; ++nt) { f32x4 z = {0.f,0.f,0.f,0.f}; acc1[nt] = z; }

    half8 aflo0 = *(const half8*)(qlog + base + (size_t)(r0 + ml) * D_MODEL + kg * 8);
    half8 aflo1 = *(const half8*)(qlog + base + (size_t)(r0 + ml) * D_MODEL + 32 + kg * 8);
    #pragma unroll
    for (int nt = 0; nt < 8; ++nt) {
        if (nt * 16 <= rowmax) {
            #pragma unroll
            for (int kit = 0; kit < 2; ++kit) {
                half8 af = *(const half8*)&sq[(r0 + ml) * 72 + kit * 32 + kg * 8];
                half8 bf = *(const half8*)&sk[(nt * 16 + ml) * 72 + kit * 32 + kg * 8];
                acc1[nt] = __builtin_amdgcn_mfma_f32_16x16x32_f16(af, bf, acc1[nt], 0, 0, 0);
            }
        }
    }
    #pragma unroll
    for (int nt = 0; nt < 8; ++nt) {
        if (nt * 16 <= rowmax) {
            const int jr = nt * 16 + ml;
            half8 bl0 = *(const half8*)&sklo[jr * 64 + ((kg ^ (jr & 7)) << 3)];
            half8 bl1 = *(const half8*)&sklo[jr * 64 + (((4 + kg) ^ (jr & 7)) << 3)];
            half8 ah0 = *(const half8*)&sq[(r0 + ml) * 72 + kg * 8];
            half8 ah1 = *(const half8*)&sq[(r0 + ml) * 72 + 32 + kg * 8];
            half8 bh0 = *(const half8*)&sk[jr * 72 + kg * 8];
            half8 bh1 = *(const half8*)&sk[jr * 72 + 32 + kg * 8];
            acc1[nt] = __builtin_amdgcn_mfma_f32_16x16x32_f16(ah0, bl0, acc1[nt], 0, 0, 0);
            acc1[nt] = __builtin_amdgcn_mfma_f32_16x16x32_f16(ah1, bl1, acc1[nt], 0, 0, 0);
            acc1[nt] = __builtin_amdgcn_mfma_f32_16x16x32_f16(aflo0, bh0, acc1[nt], 0, 0, 0);
            acc1[nt] = __builtin_amdgcn_mfma_f32_16x16x32_f16(aflo1, bh1, acc1[nt], 0, 0, 0);
        }
    }

    // ---- fused den: rowsum of masked S + q.z ----
    float rs[4];
    #pragma unroll
    for (int t = 0; t < 4; ++t) {
        const int ig = r0 + kg * 4 + t;
        float s = 0.f;
        #pragma unroll
        for (int nt = 0; nt < 8; ++nt) {
            int jg = nt * 16 + ml;
            s += (jg <= ig) ? acc1[nt][t] : 0.f;
        }
        const int f0 = ml * 4;
        half4 ql = *(const half4*)(qlog + base + (size_t)ig * D_MODEL + f0);
        #pragma unroll
        for (int u = 0; u < 4; ++u)
            s += ((float)sq[ig * 72 + f0 + u] + (float)ql[u]) * szz[f0 + u];
        s += __shfl_xor(s, 1, 64);
        s += __shfl_xor(s, 2, 64);
        s += __shfl_xor(s, 4, 64);
        s += __shfl_xor(s, 8, 64);
        rs[t] = s;
    }

    __syncthreads();   // all waves done reading sklo (=ssc) before S overwrite

    // ---- masked S -> LDS (wave-private rows) ----
    #pragma unroll
    for (int nt = 0; nt < 8; ++nt) {
        #pragma unroll
        for (int t = 0; t < 4; ++t) {
            int lr = r0 + kg * 4 + t;
            int jg = nt * 16 + ml;
            float val = (jg <= lr) ? acc1[nt][t] : 0.f;
            ssc[lr * 136 + jg] = (_Float16)val;
        }
    }
    __syncthreads();   // (safety: LDS write->read ordering across the block)

    // ---- PV + qS ----
    const int nkit = (w >> 1) + 1;
    f32x4 acc2[4];
    #pragma unroll
    for (int et = 0; et < 4; ++et) { f32x4 z = {0.f,0.f,0.f,0.f}; acc2[et] = z; }
    #pragma unroll
    for (int et = 0; et < 4; ++et) {
        for (int kit = 0; kit < nkit; ++kit) {
            half8 af = *(const half8*)&ssc[(r0 + ml) * 136 + kit * 32 + kg * 8];
            half8 bf = *(const half8*)&sv[(et * 16 + ml) * 136 + kit * 32 + kg * 8];
            acc2[et] = __builtin_amdgcn_mfma_f32_16x16x32_f16(af, bf, acc2[et], 0, 0, 0);
        }
        #pragma unroll
        for (int kit = 0; kit < 2; ++kit) {
            half8 af = *(const half8*)&sq[(r0 + ml) * 72 + kit * 32 + kg * 8];
            half8 bf = *(const half8*)&sS[(et * 16 + ml) * 72 + kit * 32 + kg * 8];
            acc2[et] = __builtin_amdgcn_mfma_f32_16x16x32_f16(af, bf, acc2[et], 0, 0, 0);
        }
    }
    #pragma unroll
    for (int t = 0; t < 4; ++t) {
        int ig = r0 + kg * 4 + t;
        float rc = 0.015625f / fmaxf(rs[t], EPS_DEN);
        #pragma unroll
        for (int et = 0; et < 4; ++et) {
            int e = et * 16 + ml;
            O16[base + (size_t)ig * D_MODEL + e] = (_Float16)(acc2[et][t] * rc);
        }
    }
}

// ---------------------------------------------------------------------------
extern "C" void kernel_launch(void* const* d_in, const int* in_sizes, int n_in,
                              void* d_out, int out_size, void* d_ws, size_t ws_size,
                              hipStream_t stream) {
    const float* x  = (const float*)d_in[0];
    const float* Wq = (const float*)d_in[1];
    const float* bq = (const float*)d_in[2];
    const float* Wk = (const float*)d_in[3];
    const float* bk = (const float*)d_in[4];
    const float* Wv = (const float*)d_in[5];
    const float* bv = (const float*)d_in[6];
    const float* Wo = (const float*)d_in[7];
    const float* bo = (const float*)d_in[8];
    float* out = (float*)d_out;

    char* p = (char*)d_ws;
    _Float16* x2   = (_Float16*)p;  p += (size_t)NTOK * 2048 * 2;
    _Float16* w2q  = (_Float16*)p;  p += (size_t)1024 * 2048 * 2;
    _Float16* w2k  = (_Float16*)p;  p += (size_t)1024 * 2048 * 2;   // contiguous after w2q
    _Float16* wv16 = (_Float16*)p;  p += (size_t)1024 * 1024 * 2;
    _Float16* wo16 = (_Float16*)p;  p += (size_t)1024 * 1024 * 2;
    _Float16* qlo  = (_Float16*)p;  p += (size_t)NTOK * 1024 * 2;
    _Float16* klo  = (_Float16*)p;  p += (size_t)NTOK * 1024 * 2;
    _Float16* q16  = (_Float16*)p;  p += (size_t)NTOK * 1024 * 2;
    _Float16* k16  = (_Float16*)p;  p += (size_t)NTOK * 1024 * 2;
    _Float16* v16  = (_Float16*)p;  p += (size_t)NTOK * 1024 * 2;
    float* kvT  = (float*)p;        p += (size_t)1024 * 4096 * 4;
    _Float16* kv16 = (_Float16*)p;  p += (size_t)1024 * 4096 * 2;
    float* ksb  = (float*)p;        p += (size_t)1024 * 64 * 4;
    float* bqk  = (float*)p;        p += 2048 * 4;
    _Float16* attn16 = x2;  // x2 dead after gemm_qkv

    prep<<<6152, 256, 0, stream>>>(x, Wq, Wk, Wv, Wo, bq, bk,
                                   x2, w2q, w2k, wv16, wo16, bqk);

    gemm_qkv<<<dim3(64, 24), 256, 0, stream>>>(x2, w2q, wv16, bqk, bv,
                                               qlo, klo, q16, k16, v16, ksb);

    chunk_stats<<<1024, 256, 0, stream>>>(k16, v16, kvT);
    scan_chunks<<<1024, 256, 0, stream>>>(kvT, kv16, ksb);
    attn_core<<<1024, 512, 0, stream>>>(q16, k16, v16, qlo, klo, kv16, ksb, attn16);

    gemm_out<<<dim3(64, 8), 256, 0, stream>>>(attn16, wo16, bo, out);
}

// Round 11
// 290.289 us; speedup vs baseline: 1.2256x; 1.0129x over previous
//
#include <hip/hip_runtime.h>
#include <math.h>

#define D_MODEL 1024
#define HEADS   16
#define HDIM    64
#define CHUNK   128
#define B_SZ    4
#define L_SEQ   2048
#define NCHUNK  16
#define NTOK    8192
#define EPS_DEN 1e-3f

typedef _Float16 half8 __attribute__((ext_vector_type(8)));
typedef _Float16 half4 __attribute__((ext_vector_type(4)));
typedef float    f32x4 __attribute__((ext_vector_type(4)));

__device__ __forceinline__ void gld_lds16(const void* g, void* l) {
    __builtin_amdgcn_global_load_lds(
        (const __attribute__((address_space(1))) void*)g,
        (__attribute__((address_space(3))) void*)l, 16, 0, 0);
}

// ---------------------------------------------------------------------------
// Fused preprocessing: x -> [hi|lo] (lo IS read by the qk GEMM — load-bearing,
// R10 lesson), Wq/Wk/Wv/Wo -> plain f16 (W-lo was dead data in R8: never read;
// eliding it is bit-identical), bias concat [bq|bk].
// ---------------------------------------------------------------------------
__global__ __launch_bounds__(256) void prep(
    const float* __restrict__ x,  const float* __restrict__ Wq,
    const float* __restrict__ Wk, const float* __restrict__ Wv,
    const float* __restrict__ Wo, const float* __restrict__ bq,
    const float* __restrict__ bk,
    _Float16* __restrict__ x2,  _Float16* __restrict__ w2q,
    _Float16* __restrict__ w2k, _Float16* __restrict__ wv16,
    _Float16* __restrict__ wo16, float* __restrict__ bqk) {
    const int bid = blockIdx.x;
    if (bid < 4096) {           // x -> hi|lo split
        int t = bid * 256 + threadIdx.x;
        int m = t >> 7, kc = (t & 127) << 3;
        const float* s = x + (size_t)m * 1024 + kc;
        f32x4 a = *(const f32x4*)s;
        f32x4 b = *(const f32x4*)(s + 4);
        float xs[8] = {a.x, a.y, a.z, a.w, b.x, b.y, b.z, b.w};
        half8 hi, lo;
        #pragma unroll
        for (int u = 0; u < 8; ++u) {
            _Float16 h = (_Float16)xs[u];
            hi[u] = h;
            lo[u] = (_Float16)(xs[u] - (float)h);
        }
        *(half8*)(x2 + (size_t)m * 2048 + kc)        = hi;
        *(half8*)(x2 + (size_t)m * 2048 + 1024 + kc) = lo;
    } else if (bid < 6144) {    // conv jobs: Wq / Wk / Wv / Wo -> f16
        const float* src; _Float16* dst; int t;
        if (bid < 4608)      { src = Wq; dst = w2q;  t = (bid - 4096) * 256 + threadIdx.x; }
        else if (bid < 5120) { src = Wk; dst = w2k;  t = (bid - 4608) * 256 + threadIdx.x; }
        else if (bid < 5632) { src = Wv; dst = wv16; t = (bid - 5120) * 256 + threadIdx.x; }
        else                 { src = Wo; dst = wo16; t = (bid - 5632) * 256 + threadIdx.x; }
        int m = t >> 7, kc = (t & 127) << 3;
        const float* s = src + (size_t)m * 1024 + kc;
        f32x4 a = *(const f32x4*)s;
        f32x4 b = *(const f32x4*)(s + 4);
        float xs[8] = {a.x, a.y, a.z, a.w, b.x, b.y, b.z, b.w};
        half8 hv;
        #pragma unroll
        for (int u = 0; u < 8; ++u) hv[u] = (_Float16)xs[u];
        *(half8*)(dst + (size_t)m * 1024 + kc) = hv;
    } else {
        int i = (bid - 6144) * 256 + threadIdx.x;
        bqk[i] = (i < 1024) ? bq[i] : bk[i - 1024];
    }
}

// ---------------------------------------------------------------------------
// Fused q/k/v projection GEMM (R8 compute path — last passing config).
// qk: 64 K-steps, K = [x_hi|x_lo] x W_hi (x-lo term is LOAD-BEARING: R10's
// removal of it failed via den-clamp amplification). v: 32 steps, x_hi x W.
// Epilogue: silu, qlo/klo = vv - f16(vv) residual stores (keep S/den
// fp32-grade in attn_core — R9 lesson), fused ksum, f16 slab transpose.
// 2-phase double buffer, 128x128 tile, 4 waves, 4 blocks/CU.
// ---------------------------------------------------------------------------
__global__ __launch_bounds__(256, 4) void gemm_qkv(
    const _Float16* __restrict__ A,    // x2, lda 2048 ([hi|lo] per row)
    const _Float16* __restrict__ Bqk,  // [w2q;w2k] stacked, ldb 1024, 2048 rows
    const _Float16* __restrict__ Bv,   // wv16, ldb 1024
    const float* __restrict__ bqk, const float* __restrict__ bv,
    _Float16* __restrict__ Qlo, _Float16* __restrict__ Klo,
    _Float16* __restrict__ Q16, _Float16* __restrict__ K16,
    _Float16* __restrict__ V16, float* __restrict__ ksum) {
    // two buffers of [A 128x32 | B 128x32] = 16KB each; slab reuses sbuf.
    __shared__ __align__(16) _Float16 sbuf[2 * 8192];
    __shared__ float sksum[2][128];
    _Float16* sC16 = sbuf;              // epilogue slab (needs 4352h <= 8192h)

    const int cb   = blockIdx.y;
    const int isqk = (cb < 16);
    const int isk  = (cb >= 8 && cb < 16);
    const int tid  = threadIdx.x;
    const int lane = tid & 63;
    const int w    = tid >> 6;
    const int row0 = blockIdx.x * 128;
    const int col0 = cb * 128;               // 0..3071 global col space
    const int wm   = (w & 1) * 64;
    const int wn   = (w >> 1) * 64;

    const _Float16* B = isqk ? Bqk : Bv;
    const int bcol0   = isqk ? col0 : col0 - 2048;
    const int kits    = isqk ? 64 : 32;   // qk: K = [x_hi|x_lo] x W_hi

    const int ch0 = w * 64 + lane;
    const int rS0 = ch0 >> 2;
    const int cS0 = (ch0 & 3) ^ ((rS0 >> 1) & 3);
    const int ch1 = ch0 + 256;
    const int rS1 = ch1 >> 2;
    const int cS1 = (ch1 & 3) ^ ((rS1 >> 1) & 3);

    const _Float16* gA0 = A + (size_t)(row0  + rS0) * 2048 + cS0 * 8;
    const _Float16* gA1 = A + (size_t)(row0  + rS1) * 2048 + cS1 * 8;
    const _Float16* gB0 = B + (size_t)(bcol0 + rS0) * 1024 + cS0 * 8;
    const _Float16* gB1 = B + (size_t)(bcol0 + rS1) * 1024 + cS1 * 8;

    auto stage = [&](int kt, int bsel) {
        const int k0   = kt * 32;
        const int acol = k0;                           // 0..2047 (hi|lo of x)
        const int bcol = (k0 < 1024) ? k0 : k0 - 1024; // W hi cols re-read
        _Float16* l = sbuf + bsel * 8192;
        gld_lds16(gA0 + acol, l + w * 512);
        gld_lds16(gA1 + acol, l + 2048 + w * 512);
        gld_lds16(gB0 + bcol, l + 4096 + w * 512);
        gld_lds16(gB1 + bcol, l + 6144 + w * 512);
    };

    f32x4 acc[4][4];
    #pragma unroll
    for (int i = 0; i < 4; ++i)
        #pragma unroll
        for (int j = 0; j < 4; ++j) { f32x4 z = {0.f, 0.f, 0.f, 0.f}; acc[i][j] = z; }

    const int ml = lane & 15;
    const int kg = lane >> 4;
    int offA[4], offB[4];
    #pragma unroll
    for (int i = 0; i < 4; ++i) {
        int r  = wm + i * 16 + ml;
        offA[i] = r * 32 + (kg ^ ((r >> 1) & 3)) * 8;
        int rn = wn + i * 16 + ml;
        offB[i] = 4096 + rn * 32 + (kg ^ ((rn >> 1) & 3)) * 8;
    }

    stage(0, 0);
    asm volatile("s_waitcnt vmcnt(0)\n\ts_barrier" ::: "memory");
    int cur = 0;
    for (int t = 0; t < kits; ++t) {
        if (t + 1 < kits) stage(t + 1, cur ^ 1);   // issue BEFORE compute
        const _Float16* lb = sbuf + cur * 8192;
        half8 af[4], bf[4];
        #pragma unroll
        for (int i = 0; i < 4; ++i) {
            af[i] = *(const half8*)&lb[offA[i]];
            bf[i] = *(const half8*)&lb[offB[i]];
        }
        __builtin_amdgcn_s_setprio(1);
        #pragma unroll
        for (int i = 0; i < 4; ++i)
            #pragma unroll
            for (int j = 0; j < 4; ++j)
                acc[i][j] = __builtin_amdgcn_mfma_f32_16x16x32_f16(af[i], bf[j], acc[i][j], 0, 0, 0);
        __builtin_amdgcn_s_setprio(0);
        asm volatile("s_waitcnt vmcnt(0)\n\ts_barrier" ::: "memory");
        cur ^= 1;
    }

    // output routing
    const int colq = isqk ? ((col0 < 1024) ? col0 : col0 - 1024) : (col0 - 2048);
    _Float16* Ylo  = (col0 < 1024) ? Qlo : Klo;      // only used when isqk
    _Float16* Y16  = isqk ? ((col0 < 1024) ? Q16 : K16) : V16;

    const int rg = lane >> 4;
    #pragma unroll
    for (int j = 0; j < 4; ++j) {
        const float bvb = isqk ? bqk[col0 + wn + j * 16 + ml]
                               : bv[colq + wn + j * 16 + ml];
        const int nn = colq + wn + j * 16 + ml;
        #pragma unroll
        for (int i = 0; i < 4; ++i) {
            #pragma unroll
            for (int t = 0; t < 4; ++t) {
                float vv = acc[i][j][t] + bvb;
                if (isqk) {
                    vv = vv / (1.f + expf(-vv));     // silu
                    int mm = row0 + wm + i * 16 + rg * 4 + t;
                    _Float16 hv = (_Float16)vv;      // hi (same cast as slab)
                    Ylo[(size_t)mm * 1024 + nn] = (_Float16)(vv - (float)hv);
                }
                acc[i][j][t] = vv;
            }
        }
    }

    // fused ksum for k-blocks: this tile = chunk (b,n) x 2 heads.
    if (isk) {
        #pragma unroll
        for (int j = 0; j < 4; ++j) {
            float ps = 0.f;
            #pragma unroll
            for (int i = 0; i < 4; ++i)
                #pragma unroll
                for (int t = 0; t < 4; ++t) ps += acc[i][j][t];
            // reduce over the 4 rg lane groups (lanes kg*16+ml)
            ps += __shfl_xor(ps, 16, 64);
            ps += __shfl_xor(ps, 32, 64);
            if (kg == 0) sksum[wm >> 6][wn + j * 16 + ml] = ps;
        }
        __syncthreads();
        if (tid < 128) {
            const int b = row0 >> 11;
            const int n = (row0 >> 7) & 15;
            const int cg = colq + tid;         // global k-col
            const int h = cg >> 6, f = cg & 63;
            ksum[(size_t)(((b * 16 + h) * 16 + n)) * 64 + f] =
                sksum[0][tid] + sksum[1][tid];
        }
        __syncthreads();
    }

    // f16 via LDS slab transpose (4 slabs of 32 rows), slab buffer = sbuf
    for (int s = 0; s < 4; ++s) {
        if ((wm == 0) == (s < 2)) {
            const int ib = (s & 1) * 2;
            #pragma unroll
            for (int ii = 0; ii < 2; ++ii)
                #pragma unroll
                for (int j = 0; j < 4; ++j)
                    #pragma unroll
                    for (int t = 0; t < 4; ++t) {
                        int lr = ii * 16 + rg * 4 + t;
                        sC16[lr * 136 + wn + j * 16 + ml] = (_Float16)acc[ib + ii][j][t];
                    }
        }
        __syncthreads();
        #pragma unroll
        for (int u = 0; u < 2; ++u) {
            int c = u * 256 + tid;
            int r = c >> 4, cc = (c & 15) * 8;
            half8 hv = *(const half8*)&sC16[r * 136 + cc];
            *(half8*)(Y16 + (size_t)(row0 + 32 * s + r) * 1024 + colq + cc) = hv;
        }
        __syncthreads();
    }
}

// ---------------------------------------------------------------------------
// Final output GEMM: out = attn16 * wo16^T * 64 + bo. Tile 128x128, BK=32,
// 2-phase double buffer. grid dim3(64, 8).
// ---------------------------------------------------------------------------
__global__ __launch_bounds__(256, 4) void gemm_out(
    const _Float16* __restrict__ A,   // attn16, lda 1024
    const _Float16* __restrict__ B,   // wo16, ldb 1024
    const float* __restrict__ bias,
    float* __restrict__ Y) {
    __shared__ __align__(16) _Float16 sbuf[2 * 8192];  // [A 128x32 | B 128x32] x2

    const int tid  = threadIdx.x;
    const int lane = tid & 63;
    const int w    = tid >> 6;
    const int row0 = blockIdx.x * 128;
    const int col0 = blockIdx.y * 128;
    const int wm   = (w & 1) * 64;
    const int wn   = (w >> 1) * 64;

    const int ch0 = w * 64 + lane;
    const int rS0 = ch0 >> 2;
    const int cS0 = (ch0 & 3) ^ ((rS0 >> 1) & 3);
    const int ch1 = ch0 + 256;
    const int rS1 = ch1 >> 2;
    const int cS1 = (ch1 & 3) ^ ((rS1 >> 1) & 3);

    const _Float16* gA0 = A + (size_t)(row0 + rS0) * 1024 + cS0 * 8;
    const _Float16* gA1 = A + (size_t)(row0 + rS1) * 1024 + cS1 * 8;
    const _Float16* gB0 = B + (size_t)(col0 + rS0) * 1024 + cS0 * 8;
    const _Float16* gB1 = B + (size_t)(col0 + rS1) * 1024 + cS1 * 8;

    auto stage = [&](int kt, int bsel) {
        const int k0 = kt * 32;
        _Float16* l = sbuf + bsel * 8192;
        gld_lds16(gA0 + k0, l + w * 512);
        gld_lds16(gA1 + k0, l + 2048 + w * 512);
        gld_lds16(gB0 + k0, l + 4096 + w * 512);
        gld_lds16(gB1 + k0, l + 6144 + w * 512);
    };

    f32x4 acc[4][4];
    #pragma unroll
    for (int i = 0; i < 4; ++i)
        #pragma unroll
        for (int j = 0; j < 4; ++j) { f32x4 z = {0.f, 0.f, 0.f, 0.f}; acc[i][j] = z; }

    const int ml = lane & 15;
    const int kg = lane >> 4;
    int offA[4], offB[4];
    #pragma unroll
    for (int i = 0; i < 4; ++i) {
        int r  = wm + i * 16 + ml;
        offA[i] = r * 32 + (kg ^ ((r >> 1) & 3)) * 8;
        int rn = wn + i * 16 + ml;
        offB[i] = 4096 + rn * 32 + (kg ^ ((rn >> 1) & 3)) * 8;
    }

    stage(0, 0);
    asm volatile("s_waitcnt vmcnt(0)\n\ts_barrier" ::: "memory");
    int cur = 0;
    for (int kit = 0; kit < 32; ++kit) {
        if (kit + 1 < 32) stage(kit + 1, cur ^ 1);
        const _Float16* lb = sbuf + cur * 8192;
        half8 af[4], bf[4];
        #pragma unroll
        for (int i = 0; i < 4; ++i) {
            af[i] = *(const half8*)&lb[offA[i]];
            bf[i] = *(const half8*)&lb[offB[i]];
        }
        __builtin_amdgcn_s_setprio(1);
        #pragma unroll
        for (int i = 0; i < 4; ++i)
            #pragma unroll
            for (int j = 0; j < 4; ++j)
                acc[i][j] = __builtin_amdgcn_mfma_f32_16x16x32_f16(af[i], bf[j], acc[i][j], 0, 0, 0);
        __builtin_amdgcn_s_setprio(0);
        asm volatile("s_waitcnt vmcnt(0)\n\ts_barrier" ::: "memory");
        cur ^= 1;
    }

    const int rg = lane >> 4;
    #pragma unroll
    for (int j = 0; j < 4; ++j) {
        const int nn = col0 + wn + j * 16 + ml;
        const float bvb = bias[nn];
        #pragma unroll
        for (int i = 0; i < 4; ++i) {
            #pragma unroll
            for (int t = 0; t < 4; ++t) {
                int mm = row0 + wm + i * 16 + rg * 4 + t;
                Y[(size_t)mm * 1024 + nn] = acc[i][j][t] * 64.f + bvb;
            }
        }
    }
}

// ---------------------------------------------------------------------------
// chunk stats: kvT[blk][e][f] = sum_j v16[j][e]*k16[j][f] via MFMA.
// ---------------------------------------------------------------------------
__global__ __launch_bounds__(256) void chunk_stats(
    const _Float16* __restrict__ k16g, const _Float16* __restrict__ v16g,
    float* __restrict__ kvT) {
    const int blk = blockIdx.x;
    const int n = blk & 15, bh = blk >> 4, h = bh & 15, b = bh >> 4;
    const size_t base = ((size_t)b * L_SEQ + (size_t)n * CHUNK) * D_MODEL + (size_t)h * HDIM;

    __shared__ __align__(16) _Float16 sv[64 * 136];
    __shared__ __align__(16) _Float16 sk[64 * 136];

    const int tid = threadIdx.x;
    #pragma unroll
    for (int p = 0; p < 4; ++p) {
        int idx = p * 256 + tid;
        int j = idx >> 3, c = idx & 7;
        half8 vv = *(const half8*)(v16g + base + (size_t)j * D_MODEL + c * 8);
        half8 kk = *(const half8*)(k16g + base + (size_t)j * D_MODEL + c * 8);
        #pragma unroll
        for (int u = 0; u < 8; ++u) {
            sv[(c * 8 + u) * 136 + j] = vv[u];
            sk[(c * 8 + u) * 136 + j] = kk[u];
        }
    }
    __syncthreads();

    const int lane = tid & 63;
    const int w    = tid >> 6;
    const int ml   = lane & 15;
    const int kg   = lane >> 4;

    f32x4 acc[4];
    #pragma unroll
    for (int ft = 0; ft < 4; ++ft) { f32x4 z = {0.f,0.f,0.f,0.f}; acc[ft] = z; }
    #pragma unroll
    for (int ft = 0; ft < 4; ++ft)
        #pragma unroll
        for (int kit = 0; kit < 4; ++kit) {
            half8 af = *(const half8*)&sv[(w * 16 + ml) * 136 + kit * 32 + kg * 8];
            half8 bf = *(const half8*)&sk[(ft * 16 + ml) * 136 + kit * 32 + kg * 8];
            acc[ft] = __builtin_amdgcn_mfma_f32_16x16x32_f16(af, bf, acc[ft], 0, 0, 0);
        }
    float* o = kvT + (size_t)blk * 4096;
    #pragma unroll
    for (int ft = 0; ft < 4; ++ft)
        #pragma unroll
        for (int t = 0; t < 4; ++t) {
            int e = w * 16 + kg * 4 + t;
            o[e * 64 + ft * 16 + ml] = acc[ft][t];
        }
}

// ---------------------------------------------------------------------------
// Exclusive cumsum over chunk axis; emits prefix directly as f16.
// ---------------------------------------------------------------------------
__global__ __launch_bounds__(256) void scan_chunks(const float* __restrict__ kvT,
                                                   _Float16* __restrict__ kv16,
                                                   float* __restrict__ ksum) {
    const int bh  = blockIdx.x >> 4;
    const int seg = blockIdx.x & 15;
    const int idx = seg * 256 + threadIdx.x;
    const float* base = kvT + (size_t)bh * NCHUNK * 4096 + idx;
    _Float16*   obase = kv16 + (size_t)bh * NCHUNK * 4096 + idx;
    float run = 0.f;
    #pragma unroll
    for (int nn = 0; nn < NCHUNK; ++nn) {
        float t = base[(size_t)nn * 4096];
        obase[(size_t)nn * 4096] = (_Float16)run;
        run += t;
    }
    if (seg == 0 && threadIdx.x < 64) {
        float* zb = ksum + (size_t)bh * NCHUNK * 64 + threadIdx.x;
        float r2 = 0.f;
        #pragma unroll
        for (int nn = 0; nn < NCHUNK; ++nn) {
            float t = zb[nn * 64];
            zb[nn * 64] = r2;
            r2 += t;
        }
    }
}

// ---------------------------------------------------------------------------
// MFMA attention core, 8-wave single-pass with fp32-grade S/den (R8 version —
// the compensation is load-bearing: R9's removal failed 1757 > 711).
// ---------------------------------------------------------------------------
__global__ __launch_bounds__(512) void attn_core(
    const _Float16* __restrict__ q16g, const _Float16* __restrict__ k16g,
    const _Float16* __restrict__ v16g, const _Float16* __restrict__ qlog,
    const _Float16* __restrict__ klog, const _Float16* __restrict__ ST16,
    const float* __restrict__ zg, _Float16* __restrict__ O16) {
    const int blk = blockIdx.x;
    const int n = blk & 15, bh = blk >> 4, h = bh & 15, b = bh >> 4;
    const size_t base = ((size_t)b * L_SEQ + (size_t)n * CHUNK) * D_MODEL + (size_t)h * HDIM;

    __shared__ __align__(16) _Float16 sq [128 * 72];
    __shared__ __align__(16) _Float16 sk [128 * 72];
    __shared__ __align__(16) _Float16 sv [64 * 136];
    __shared__ __align__(16) _Float16 sS [64 * 72];
    __shared__ __align__(16) _Float16 ssc[128 * 136];  // S stage; aliases klo stage
    __shared__ float szz[64];
    _Float16* sklo = ssc;   // klo[j][chunk c] at j*64 + ((c^(j&7))<<3); 8192h

    const int tid = threadIdx.x;
    #pragma unroll
    for (int p = 0; p < 2; ++p) {
        int idx = p * 512 + tid;
        int j = idx >> 3, c = idx & 7;
        *(half8*)&sq[j * 72 + c * 8] = *(const half8*)(q16g + base + (size_t)j * D_MODEL + c * 8);
        *(half8*)&sk[j * 72 + c * 8] = *(const half8*)(k16g + base + (size_t)j * D_MODEL + c * 8);
        half8 vv = *(const half8*)(v16g + base + (size_t)j * D_MODEL + c * 8);
        #pragma unroll
        for (int u = 0; u < 8; ++u) sv[(c * 8 + u) * 136 + j] = vv[u];
        half8 kl = *(const half8*)(klog + base + (size_t)j * D_MODEL + c * 8);
        *(half8*)&sklo[j * 64 + ((c ^ (j & 7)) << 3)] = kl;
    }
    {
        int e = tid >> 3, c = tid & 7;
        *(half8*)&sS[e * 72 + c * 8] =
            *(const half8*)(ST16 + (size_t)blk * 4096 + e * 64 + c * 8);
    }
    if (tid < 64) szz[tid] = zg[(size_t)blk * 64 + tid];
    __syncthreads();

    const int lane = tid & 63;
    const int w    = tid >> 6;          // 0..7, owns rows w*16..w*16+15
    const int ml   = lane & 15;
    const int kg   = lane >> 4;
    const int r0   = w * 16;
    const int rowmax = r0 + 15;

    // ---- QK^T: hi*hi + hi*lo + lo*hi (klo from LDS) ----
    f32x4 acc1[8];
    #pragma unroll
    for (int nt = 0; nt < 8; ++nt) { f32x4 z = {0.f,0.f,0.f,0.f}; acc1[nt] = z; }

    half8 aflo0 = *(const half8*)(qlog + base + (size_t)(r0 + ml) * D_MODEL + kg * 8);
    half8 aflo1 = *(const half8*)(qlog + base + (size_t)(r0 + ml) * D_MODEL + 32 + kg * 8);
    #pragma unroll
    for (int nt = 0; nt < 8; ++nt) {
        if (nt * 16 <= rowmax) {
            #pragma unroll
            for (int kit = 0; kit < 2; ++kit) {
                half8 af = *(const half8*)&sq[(r0 + ml) * 72 + kit * 32 + kg * 8];
                half8 bf = *(const half8*)&sk[(nt * 16 + ml) * 72 + kit * 32 + kg * 8];
                acc1[nt] = __builtin_amdgcn_mfma_f32_16x16x32_f16(af, bf, acc1[nt], 0, 0, 0);
            }
        }
    }
    #pragma unroll
    for (int nt = 0; nt < 8; ++nt) {
        if (nt * 16 <= rowmax) {
            const int jr = nt * 16 + ml;
            half8 bl0 = *(const half8*)&sklo[jr * 64 + ((kg ^ (jr & 7)) << 3)];
            half8 bl1 = *(const half8*)&sklo[jr * 64 + (((4 + kg) ^ (jr & 7)) << 3)];
            half8 ah0 = *(const half8*)&sq[(r0 + ml) * 72 + kg * 8];
            half8 ah1 = *(const half8*)&sq[(r0 + ml) * 72 + 32 + kg * 8];
            half8 bh0 = *(const half8*)&sk[jr * 72 + kg * 8];
            half8 bh1 = *(const half8*)&sk[jr * 72 + 32 + kg * 8];
            acc1[nt] = __builtin_amdgcn_mfma_f32_16x16x32_f16(ah0, bl0, acc1[nt], 0, 0, 0);
            acc1[nt] = __builtin_amdgcn_mfma_f32_16x16x32_f16(ah1, bl1, acc1[nt], 0, 0, 0);
            acc1[nt] = __builtin_amdgcn_mfma_f32_16x16x32_f16(aflo0, bh0, acc1[nt], 0, 0, 0);
            acc1[nt] = __builtin_amdgcn_mfma_f32_16x16x32_f16(aflo1, bh1, acc1[nt], 0, 0, 0);
        }
    }

    // ---- fused den: rowsum of masked S + q.z ----
    float rs[4];
    #pragma unroll
    for (int t = 0; t < 4; ++t) {
        const int ig = r0 + kg * 4 + t;
        float s = 0.f;
        #pragma unroll
        for (int nt = 0; nt < 8; ++nt) {
            int jg = nt * 16 + ml;
            s += (jg <= ig) ? acc1[nt][t] : 0.f;
        }
        const int f0 = ml * 4;
        half4 ql = *(const half4*)(qlog + base + (size_t)ig * D_MODEL + f0);
        #pragma unroll
        for (int u = 0; u < 4; ++u)
            s += ((float)sq[ig * 72 + f0 + u] + (float)ql[u]) * szz[f0 + u];
        s += __shfl_xor(s, 1, 64);
        s += __shfl_xor(s, 2, 64);
        s += __shfl_xor(s, 4, 64);
        s += __shfl_xor(s, 8, 64);
        rs[t] = s;
    }

    __syncthreads();   // all waves done reading sklo (=ssc) before S overwrite

    // ---- masked S -> LDS (wave-private rows) ----
    #pragma unroll
    for (int nt = 0; nt < 8; ++nt) {
        #pragma unroll
        for (int t = 0; t < 4; ++t) {
            int lr = r0 + kg * 4 + t;
            int jg = nt * 16 + ml;
            float val = (jg <= lr) ? acc1[nt][t] : 0.f;
            ssc[lr * 136 + jg] = (_Float16)val;
        }
    }
    __syncthreads();

    // ---- PV + qS ----
    const int nkit = (w >> 1) + 1;
    f32x4 acc2[4];
    #pragma unroll
    for (int et = 0; et < 4; ++et) { f32x4 z = {0.f,0.f,0.f,0.f}; acc2[et] = z; }
    #pragma unroll
    for (int et = 0; et < 4; ++et) {
        for (int kit = 0; kit < nkit; ++kit) {
            half8 af = *(const half8*)&ssc[(r0 + ml) * 136 + kit * 32 + kg * 8];
            half8 bf = *(const half8*)&sv[(et * 16 + ml) * 136 + kit * 32 + kg * 8];
            acc2[et] = __builtin_amdgcn_mfma_f32_16x16x32_f16(af, bf, acc2[et], 0, 0, 0);
        }
        #pragma unroll
        for (int kit = 0; kit < 2; ++kit) {
            half8 af = *(const half8*)&sq[(r0 + ml) * 72 + kit * 32 + kg * 8];
            half8 bf = *(const half8*)&sS[(et * 16 + ml) * 72 + kit * 32 + kg * 8];
            acc2[et] = __builtin_amdgcn_mfma_f32_16x16x32_f16(af, bf, acc2[et], 0, 0, 0);
        }
    }
    #pragma unroll
    for (int t = 0; t < 4; ++t) {
        int ig = r0 + kg * 4 + t;
        float rc = 0.015625f / fmaxf(rs[t], EPS_DEN);
        #pragma unroll
        for (int et = 0; et < 4; ++et) {
            int e = et * 16 + ml;
            O16[base + (size_t)ig * D_MODEL + e] = (_Float16)(acc2[et][t] * rc);
        }
    }
}

// ---------------------------------------------------------------------------
extern "C" void kernel_launch(void* const* d_in, const int* in_sizes, int n_in,
                              void* d_out, int out_size, void* d_ws, size_t ws_size,
                              hipStream_t stream) {
    const float* x  = (const float*)d_in[0];
    const float* Wq = (const float*)d_in[1];
    const float* bq = (const float*)d_in[2];
    const float* Wk = (const float*)d_in[3];
    const float* bk = (const float*)d_in[4];
    const float* Wv = (const float*)d_in[5];
    const float* bv = (const float*)d_in[6];
    const float* Wo = (const float*)d_in[7];
    const float* bo = (const float*)d_in[8];
    float* out = (float*)d_out;

    char* p = (char*)d_ws;
    _Float16* x2   = (_Float16*)p;  p += (size_t)NTOK * 2048 * 2;   // [hi|lo]
    _Float16* w2q  = (_Float16*)p;  p += (size_t)1024 * 1024 * 2;
    _Float16* w2k  = (_Float16*)p;  p += (size_t)1024 * 1024 * 2;   // contiguous after w2q
    _Float16* wv16 = (_Float16*)p;  p += (size_t)1024 * 1024 * 2;
    _Float16* wo16 = (_Float16*)p;  p += (size_t)1024 * 1024 * 2;
    _Float16* qlo  = (_Float16*)p;  p += (size_t)NTOK * 1024 * 2;
    _Float16* klo  = (_Float16*)p;  p += (size_t)NTOK * 1024 * 2;
    _Float16* q16  = (_Float16*)p;  p += (size_t)NTOK * 1024 * 2;
    _Float16* k16  = (_Float16*)p;  p += (size_t)NTOK * 1024 * 2;
    _Float16* v16  = (_Float16*)p;  p += (size_t)NTOK * 1024 * 2;
    float* kvT  = (float*)p;        p += (size_t)1024 * 4096 * 4;
    _Float16* kv16 = (_Float16*)p;  p += (size_t)1024 * 4096 * 2;
    float* ksb  = (float*)p;        p += (size_t)1024 * 64 * 4;
    float* bqk  = (float*)p;        p += 2048 * 4;
    _Float16* attn16 = x2;  // x2 dead after gemm_qkv

    prep<<<6152, 256, 0, stream>>>(x, Wq, Wk, Wv, Wo, bq, bk,
                                   x2, w2q, w2k, wv16, wo16, bqk);

    gemm_qkv<<<dim3(64, 24), 256, 0, stream>>>(x2, w2q, wv16, bqk, bv,
                                               qlo, klo, q16, k16, v16, ksb);

    chunk_stats<<<1024, 256, 0, stream>>>(k16, v16, kvT);
    scan_chunks<<<1024, 256, 0, stream>>>(kvT, kv16, ksb);
    attn_core<<<1024, 512, 0, stream>>>(q16, k16, v16, qlo, klo, kv16, ksb, attn16);

    gemm_out<<<dim3(64, 8), 256, 0, stream>>>(attn16, wo16, bo, out);
}